// Round 11
// baseline (890.094 us; speedup 1.0000x reference)
//
#include <hip/hip_runtime.h>
#include <hip/hip_bf16.h>

// Sizes (fixed per problem)
#define Bz 64
#define Sz 256
#define Ez 256
#define Hz 256
#define Lz 1024
#define VLz 16

// split-precision scale: x stored as hi+lo of (x*SCL); products carry SCL^2
#define SCL 64.0f
#define DESCL (1.0f / 4096.0f)

typedef _Float16 half2_t __attribute__((ext_vector_type(2)));
typedef _Float16 half4_t __attribute__((ext_vector_type(4)));
typedef _Float16 f16x8   __attribute__((ext_vector_type(8)));
typedef float    f32x4   __attribute__((ext_vector_type(4)));

__device__ inline float fdot2(half2_t a, half2_t b, float c) {
#if __has_builtin(__builtin_amdgcn_fdot2)
    return __builtin_amdgcn_fdot2(a, b, c, false);
#else
    return c + (float)a[0] * (float)b[0] + (float)a[1] * (float)b[1];
#endif
}

// async global->LDS 16B; LDS dest must be linear lane-ordered (m104/m173)
__device__ inline void stage16(_Float16* ldst, const _Float16* gsrc) {
#if __has_builtin(__builtin_amdgcn_global_load_lds)
    __builtin_amdgcn_global_load_lds(
        (const __attribute__((address_space(1))) unsigned int*)gsrc,
        (__attribute__((address_space(3))) unsigned int*)ldst, 16, 0, 0);
#else
    *(f16x8*)ldst = *(const f16x8*)gsrc;
#endif
}

// ---------------------------------------------------------------------------
// K1: Vsum[l,e] = sum_j emb[V_idx[l,j], e]; norms; hi/lo split copy
__global__ void vsum_kernel(const int* __restrict__ V_idx, const float* __restrict__ emb,
                            float* __restrict__ Vsum, _Float16* __restrict__ vsh,
                            _Float16* __restrict__ vsl, float* __restrict__ vnorm)
{
    int l = blockIdx.x, e = threadIdx.x;
    float s = 0.f;
#pragma unroll
    for (int j = 0; j < VLz; ++j) {
        int idx = V_idx[l * VLz + j];
        s += emb[(long)idx * Ez + e];
    }
    Vsum[l * Ez + e] = s;
    float t = s * SCL;
    _Float16 h = (_Float16)t;
    vsh[l * Ez + e] = h;
    vsl[l * Ez + e] = (_Float16)(t - (float)h);
    __shared__ float red[256];
    red[e] = s * s; __syncthreads();
    for (int off = 128; off > 0; off >>= 1) { if (e < off) red[e] += red[e + off]; __syncthreads(); }
    if (e == 0) vnorm[l] = sqrtf(red[0]);
}

// K2: xe gather, hi/lo
__global__ void xe_kernel(const int* __restrict__ x, const float* __restrict__ emb,
                          _Float16* __restrict__ xeh, _Float16* __restrict__ xel)
{
    int i = blockIdx.x;              // b*S+s
    int e = threadIdx.x;
    float v = emb[(long)x[i] * Ez + e] * SCL;
    _Float16 h = (_Float16)v;
    xeh[(long)i * Ez + e] = h;
    xel[(long)i * Ez + e] = (_Float16)(v - (float)h);
}

// K3: pack w_hh [768,256] fp32 -> f16x2 in 16B-chunk order for the GRU.
// Logical dword (q-half, m = jj*6 + g*2 + p) holds
// (W[g*256+t][k], W[g*256+t][k+1]), k = 4*(q*32+jj) + 2*p — same values/order
// as the round-4 pack, but stored so each thread's dwords 4ch..4ch+3 are one
// contiguous 16B cell: dword index ((q*48+ch)*256 + t)*4 + pos.
__global__ void wpack4_kernel(const float* __restrict__ w_f, const float* __restrict__ w_b,
                              half2_t* __restrict__ out_f, half2_t* __restrict__ out_b)
{
    int i = blockIdx.x * 256 + threadIdx.x;   // 0 .. 98303
    int t = i & 255;
    int rest = i >> 8;          // kq*6 + g*2 + p, 0..383
    int p = rest & 1;
    int gq = rest >> 1;
    int g = gq % 3;
    int kq = gq / 3;
    int o = g * 256 + t;
    int k = 4 * kq + 2 * p;
    int q  = rest / 192;
    int m  = rest % 192;
    int ch = m >> 2, pos = m & 3;
    int ni = ((q * 48 + ch) * 256 + t) * 4 + pos;
    out_f[ni] = half2_t{(_Float16)w_f[o * 256 + k], (_Float16)w_f[o * 256 + k + 1]};
    out_b[ni] = half2_t{(_Float16)w_b[o * 256 + k], (_Float16)w_b[o * 256 + k + 1]};
}

// f32 -> scaled hi/lo f16
__global__ void cvtsplit_kernel(const float* __restrict__ in, _Float16* __restrict__ hi,
                                _Float16* __restrict__ lo, int n)
{
    int i = blockIdx.x * 256 + threadIdx.x;
    if (i < n) {
        float v = in[i] * SCL;
        _Float16 h = (_Float16)v;
        hi[i] = h;
        lo[i] = (_Float16)(v - (float)h);
    }
}

// ---------------------------------------------------------------------------
// Split-precision MFMA NT GEMM (round-4 proven): C = (1/4096)*(Ah+Al)@(Bh+Bl)^T.
// acc = Ah*Bh + Ah*Bl (+ Al*Bh if SPLIT_A). BM=BN=128, BK=32, 4 waves 2x2.
// OUTM: 0 = f32 C, 1 = scaled hi/lo f16 (Ch,Cl), 2 = scaled hi f16 only.
// bias_b: alternate bias selected when blockIdx.z==1 (merged f/b dispatches).
template<int EPI, int BIAS, int OUTM, int SPLIT_A>
__global__ __launch_bounds__(256, 2) void gemm_mfma(
    const _Float16* __restrict__ Ah, const _Float16* __restrict__ Al,
    const _Float16* __restrict__ Bh, const _Float16* __restrict__ Bl,
    const float* __restrict__ bias, const float* __restrict__ bias_b,
    float* __restrict__ C, _Float16* __restrict__ Ch, _Float16* __restrict__ Cl,
    int M, int N, int K, long sA, long sB, long sC)
{
    int bz = blockIdx.z;
    Ah += (long)bz * sA;
    if (SPLIT_A) Al += (long)bz * sA;
    Bh += (long)bz * sB;
    Bl += (long)bz * sB;
    const float* bp = BIAS ? (bz ? bias_b : bias) : nullptr;
    __shared__ __attribute__((aligned(16))) _Float16 Ash[128 * 32];
    __shared__ __attribute__((aligned(16))) _Float16 Asl[128 * 32];
    __shared__ __attribute__((aligned(16))) _Float16 Bsh[128 * 32];
    __shared__ __attribute__((aligned(16))) _Float16 Bsl[128 * 32];
    int tid = threadIdx.x;
    int lane = tid & 63;
    int wid = tid >> 6;
    int wm = wid >> 1, wn = wid & 1;
    int m0 = blockIdx.y * 128, n0 = blockIdx.x * 128;

    int srow = tid >> 2, sslot = tid & 3;
    int sw0 = sslot ^ ((srow >> 1) & 3);
    long a0 = (long)(m0 + srow) * K + sw0 * 8;
    long a1 = (long)(m0 + 64 + srow) * K + sw0 * 8;
    long b0 = (long)(n0 + srow) * K + sw0 * 8;
    long b1 = (long)(n0 + 64 + srow) * K + sw0 * 8;

    f32x4 acc[4][4] = {};
    int r16 = lane & 15, kg = lane >> 4;

    for (int k0 = 0; k0 < K; k0 += 32) {
        stage16(&Ash[tid * 8],        Ah + a0 + k0);
        stage16(&Ash[2048 + tid * 8], Ah + a1 + k0);
        if (SPLIT_A) {
            stage16(&Asl[tid * 8],        Al + a0 + k0);
            stage16(&Asl[2048 + tid * 8], Al + a1 + k0);
        }
        stage16(&Bsh[tid * 8],        Bh + b0 + k0);
        stage16(&Bsh[2048 + tid * 8], Bh + b1 + k0);
        stage16(&Bsl[tid * 8],        Bl + b0 + k0);
        stage16(&Bsl[2048 + tid * 8], Bl + b1 + k0);
        __syncthreads();
        f16x8 afh[4], afl[4], bfh[4], bfl[4];
#pragma unroll
        for (int mi = 0; mi < 4; ++mi) {
            int r = wm * 64 + mi * 16 + r16;
            int sl = kg ^ ((r >> 1) & 3);
            int off = r * 32 + sl * 8;
            afh[mi] = *(const f16x8*)&Ash[off];
            if (SPLIT_A) afl[mi] = *(const f16x8*)&Asl[off];
        }
#pragma unroll
        for (int ni = 0; ni < 4; ++ni) {
            int n = wn * 64 + ni * 16 + r16;
            int sl = kg ^ ((n >> 1) & 3);
            int off = n * 32 + sl * 8;
            bfh[ni] = *(const f16x8*)&Bsh[off];
            bfl[ni] = *(const f16x8*)&Bsl[off];
        }
#pragma unroll
        for (int mi = 0; mi < 4; ++mi)
#pragma unroll
            for (int ni = 0; ni < 4; ++ni) {
                acc[mi][ni] = __builtin_amdgcn_mfma_f32_16x16x32_f16(afh[mi], bfh[ni], acc[mi][ni], 0, 0, 0);
                acc[mi][ni] = __builtin_amdgcn_mfma_f32_16x16x32_f16(afh[mi], bfl[ni], acc[mi][ni], 0, 0, 0);
                if (SPLIT_A)
                    acc[mi][ni] = __builtin_amdgcn_mfma_f32_16x16x32_f16(afl[mi], bfh[ni], acc[mi][ni], 0, 0, 0);
            }
        __syncthreads();
    }

    long coff = (long)bz * sC;
#pragma unroll
    for (int mi = 0; mi < 4; ++mi) {
#pragma unroll
        for (int ni = 0; ni < 4; ++ni) {
            int n = n0 + wn * 64 + ni * 16 + r16;
            float bv = BIAS ? bp[n] : 0.f;
#pragma unroll
            for (int j = 0; j < 4; ++j) {
                int m = m0 + wm * 64 + mi * 16 + kg * 4 + j;
                float v = acc[mi][ni][j] * DESCL + bv;
                if (EPI == 1) v = fmaxf(v, 0.f);
                if (EPI == 2) v = tanhf(v);
                long idx = coff + (long)m * N + n;
                if (OUTM == 0) {
                    C[idx] = v;
                } else if (OUTM == 1) {
                    float t = v * SCL;
                    _Float16 h = (_Float16)t;
                    Ch[idx] = h;
                    Cl[idx] = (_Float16)(t - (float)h);
                } else {
                    Ch[idx] = (_Float16)(v * SCL);
                }
            }
        }
    }
}

// ---------------------------------------------------------------------------
// K4: GRU recurrence — batch-paired. 64 blocks: block = (dir, batch-pair b0,b0+1).
// 512 threads = 8 waves, k-split 2: thread (q,t) computes k-half q partials for
// BOTH batches (one weight fetch serves two batches: per-batch L2 traffic
// halves vs round-4's 12.9 GB). Weights streamed as 48 dwordx4 chunks/thread/
// step (4x fewer requests than round-4's 192 dword loads). Gate tail parallel:
// thread-half q owns batch q's gates, hprev in-register. 2 barriers/step.
// Disambiguation experiment: per-XCD-L2-bound -> ~190us; per-CU-byte-bound ->
// ~361us (round-4 floor).
__global__ __launch_bounds__(512, 2) void gru_kernel(
    const float* __restrict__ gx_f, const float* __restrict__ gx_b,
    const f16x8* __restrict__ wq4_f, const f16x8* __restrict__ wq4_b,
    const float* __restrict__ bhh_f, const float* __restrict__ bhh_b,
    _Float16* __restrict__ dh_out, _Float16* __restrict__ dl_out)
{
    int dir = blockIdx.x >> 5;
    int b0  = (blockIdx.x & 31) * 2;
    const float* gx  = dir ? gx_b : gx_f;
    const f16x8* wq4 = dir ? wq4_b : wq4_f;
    const float* bhh = dir ? bhh_b : bhh_f;
    int tid = threadIdx.x;
    int t = tid & 255, q = tid >> 8;

    __shared__ __attribute__((aligned(16))) _Float16 hbuf[2][256];   // [batch][t]
    __shared__ float part[12 * 256];   // [batch][khalf][gate][t]
#define PART(beta, qq, g) (((((beta) * 2 + (qq)) * 3 + (g)) << 8))

    const f16x8* w4 = wq4 + (size_t)q * 48 * 256 + t;

    float br = bhh[t], bz = bhh[256 + t], bn = bhh[512 + t];
    float hprev = 0.f;                 // h[batch q][t]
    if (q == 0) { hbuf[0][t] = (_Float16)0.f; hbuf[1][t] = (_Float16)0.f; }
    __syncthreads();

    for (int step = 0; step < Sz; ++step) {
        int s = dir ? (Sz - 1 - step) : step;
        // deferred previous-step d write for batch q (overlaps dot phase)
        if (step > 0) {
            int sp = dir ? (Sz - step) : (step - 1);
            float hv = hprev * SCL;
            _Float16 hh = (_Float16)hv;
            size_t idx = (size_t)((b0 + q) * Sz + sp) * 512 + dir * 256 + t;
            dh_out[idx] = hh;
            dl_out[idx] = (_Float16)(hv - (float)hh);
        }
        // gate-x loads for this step, batch q (in flight during dots)
        const float* g = gx + (size_t)((b0 + q) * Sz + s) * 768;
        float xr = g[t], xz = g[256 + t], xn = g[512 + t];

        float ar0 = 0.f, az0 = 0.f, an0 = 0.f;
        float ar1 = 0.f, az1 = 0.f, an1 = 0.f;
        const half4_t* h0q = (const half4_t*)hbuf[0] + q * 32;
        const half4_t* h1q = (const half4_t*)hbuf[1] + q * 32;
#pragma unroll
        for (int cj = 0; cj < 16; ++cj) {
            f16x8 c0 = w4[(3 * cj + 0) * 256];
            f16x8 c1 = w4[(3 * cj + 1) * 256];
            f16x8 c2 = w4[(3 * cj + 2) * 256];
            half4_t ha0 = h0q[2 * cj], hb0 = h0q[2 * cj + 1];
            half4_t ha1 = h1q[2 * cj], hb1 = h1q[2 * cj + 1];
            half2_t a01_0 = {ha0[0], ha0[1]}, a23_0 = {ha0[2], ha0[3]};
            half2_t b01_0 = {hb0[0], hb0[1]}, b23_0 = {hb0[2], hb0[3]};
            half2_t a01_1 = {ha1[0], ha1[1]}, a23_1 = {ha1[2], ha1[3]};
            half2_t b01_1 = {hb1[0], hb1[1]}, b23_1 = {hb1[2], hb1[3]};
            // batch 0
            ar0 = fdot2(half2_t{c0[0], c0[1]}, a01_0, ar0);
            ar0 = fdot2(half2_t{c0[2], c0[3]}, a23_0, ar0);
            az0 = fdot2(half2_t{c0[4], c0[5]}, a01_0, az0);
            az0 = fdot2(half2_t{c0[6], c0[7]}, a23_0, az0);
            an0 = fdot2(half2_t{c1[0], c1[1]}, a01_0, an0);
            an0 = fdot2(half2_t{c1[2], c1[3]}, a23_0, an0);
            ar0 = fdot2(half2_t{c1[4], c1[5]}, b01_0, ar0);
            ar0 = fdot2(half2_t{c1[6], c1[7]}, b23_0, ar0);
            az0 = fdot2(half2_t{c2[0], c2[1]}, b01_0, az0);
            az0 = fdot2(half2_t{c2[2], c2[3]}, b23_0, az0);
            an0 = fdot2(half2_t{c2[4], c2[5]}, b01_0, an0);
            an0 = fdot2(half2_t{c2[6], c2[7]}, b23_0, an0);
            // batch 1 (same weights)
            ar1 = fdot2(half2_t{c0[0], c0[1]}, a01_1, ar1);
            ar1 = fdot2(half2_t{c0[2], c0[3]}, a23_1, ar1);
            az1 = fdot2(half2_t{c0[4], c0[5]}, a01_1, az1);
            az1 = fdot2(half2_t{c0[6], c0[7]}, a23_1, az1);
            an1 = fdot2(half2_t{c1[0], c1[1]}, a01_1, an1);
            an1 = fdot2(half2_t{c1[2], c1[3]}, a23_1, an1);
            ar1 = fdot2(half2_t{c1[4], c1[5]}, b01_1, ar1);
            ar1 = fdot2(half2_t{c1[6], c1[7]}, b23_1, ar1);
            az1 = fdot2(half2_t{c2[0], c2[1]}, b01_1, az1);
            az1 = fdot2(half2_t{c2[2], c2[3]}, b23_1, az1);
            an1 = fdot2(half2_t{c2[4], c2[5]}, b01_1, an1);
            an1 = fdot2(half2_t{c2[6], c2[7]}, b23_1, an1);
        }
        part[PART(0, q, 0) + t] = ar0;
        part[PART(0, q, 1) + t] = az0;
        part[PART(0, q, 2) + t] = an0;
        part[PART(1, q, 0) + t] = ar1;
        part[PART(1, q, 1) + t] = az1;
        part[PART(1, q, 2) + t] = an1;
        __syncthreads();

        // gates: thread-half q handles batch q
        {
            float hr = part[PART(q, 0, 0) + t] + part[PART(q, 1, 0) + t];
            float hz = part[PART(q, 0, 1) + t] + part[PART(q, 1, 1) + t];
            float hn = part[PART(q, 0, 2) + t] + part[PART(q, 1, 2) + t];
            float r  = 1.f / (1.f + expf(-(xr + br + hr)));
            float z  = 1.f / (1.f + expf(-(xz + bz + hz)));
            float nn = tanhf(xn + r * (hn + bn));
            hprev = (1.f - z) * nn + z * hprev;
            hbuf[q][t] = (_Float16)hprev;
        }
        __syncthreads();
    }
    // final step's d write
    {
        int sl = dir ? 0 : (Sz - 1);
        float hv = hprev * SCL;
        _Float16 hh = (_Float16)hv;
        size_t idx = (size_t)((b0 + q) * Sz + sl) * 512 + dir * 256 + t;
        dh_out[idx] = hh;
        dl_out[idx] = (_Float16)(hv - (float)hh);
    }
#undef PART
}

// ---------------------------------------------------------------------------
// transpose d (hi,lo) [B*S][512] -> dT (hi,lo) [B][512][256]
__global__ __launch_bounds__(256) void dtrans_kernel(
    const _Float16* __restrict__ dh, const _Float16* __restrict__ dl,
    _Float16* __restrict__ dTh, _Float16* __restrict__ dTl)
{
    __shared__ _Float16 th[64][68];
    __shared__ _Float16 tl[64][68];
    int s0 = blockIdx.x << 6;
    int h0 = blockIdx.y << 6;
    int b  = blockIdx.z;
    int tid = threadIdx.x;
#pragma unroll
    for (int i = 0; i < 16; ++i) {
        int idx = tid + i * 256;
        int s = idx >> 6, h = idx & 63;
        size_t gi = (size_t)(b * 256 + s0 + s) * 512 + h0 + h;
        th[s][h] = dh[gi];
        tl[s][h] = dl[gi];
    }
    __syncthreads();
#pragma unroll
    for (int i = 0; i < 16; ++i) {
        int idx = tid + i * 256;
        int h = idx >> 6, s = idx & 63;
        size_t gi = (size_t)(b * 512 + h0 + h) * 256 + s0 + s;
        dTh[gi] = th[s][h];
        dTl[gi] = tl[s][h];
    }
}

// ---------------------------------------------------------------------------
// BN stats over (b, e) for each channel c (layout y[b][CH][256])
__global__ void bn_stats_kernel(const float* __restrict__ y, int CH,
                                float* __restrict__ mean, float* __restrict__ istd)
{
    int c = blockIdx.x, t = threadIdx.x;
    float s = 0.f, ss = 0.f;
    for (int b = 0; b < Bz; ++b) {
        float v = y[((long)b * CH + c) * 256 + t];
        s += v; ss += v * v;
    }
    __shared__ float rs[256], rss[256];
    rs[t] = s; rss[t] = ss; __syncthreads();
    for (int off = 128; off > 0; off >>= 1) {
        if (t < off) { rs[t] += rs[t + off]; rss[t] += rss[t + off]; }
        __syncthreads();
    }
    if (t == 0) {
        float cnt = (float)(Bz * 256);
        float m = rs[0] / cnt;
        float var = rss[0] / cnt - m * m;
        mean[c] = m;
        istd[c] = rsqrtf(var + 1e-5f);
    }
}

// BN1 apply + relu -> scaled hi/lo f16
__global__ void bn_apply_relu_kernel(const float* __restrict__ y,
                                     _Float16* __restrict__ yh, _Float16* __restrict__ yl,
                                     const float* __restrict__ mean, const float* __restrict__ istd,
                                     const float* __restrict__ g, const float* __restrict__ be)
{
    long i = (long)blockIdx.x * 256 + threadIdx.x;
    int c = (int)((i >> 8) % Sz);
    float v = (y[i] - mean[c]) * istd[c] * g[c] + be[c];
    v = fmaxf(v, 0.f);
    float t = v * SCL;
    _Float16 h = (_Float16)t;
    yh[i] = h;
    yl[i] = (_Float16)(t - (float)h);
}

// ---------------------------------------------------------------------------
// Fused BN2-apply + tanh + cosine-similarity output
__global__ void bn_tanh_out_kernel(const float* __restrict__ epre,
                                   const float* __restrict__ mean, const float* __restrict__ istd,
                                   const float* __restrict__ g, const float* __restrict__ be,
                                   const float* __restrict__ Vsum, const float* __restrict__ vnorm,
                                   float* __restrict__ out)
{
    int bl = blockIdx.x;               // b*Lz + l
    int l = bl & (Lz - 1);
    int t = threadIdx.x;
    float v = (epre[(long)bl * 256 + t] - mean[l]) * istd[l] * g[l] + be[l];
    float ev = tanhf(v);
    float vv = Vsum[l * 256 + t];
    __shared__ float rd[256], rn[256];
    rd[t] = ev * vv; rn[t] = ev * ev; __syncthreads();
    for (int off = 128; off > 0; off >>= 1) {
        if (t < off) { rd[t] += rd[t + off]; rn[t] += rn[t + off]; }
        __syncthreads();
    }
    if (t == 0) {
        float num = rd[0];
        float den = fmaxf(sqrtf(rn[0]), 1e-8f) * fmaxf(vnorm[l], 1e-8f);
        out[bl] = num / den * 10.f;
    }
}

// ---------------------------------------------------------------------------
extern "C" void kernel_launch(void* const* d_in, const int* in_sizes, int n_in,
                              void* d_out, int out_size, void* d_ws, size_t ws_size,
                              hipStream_t stream)
{
    const int*   x      = (const int*)d_in[0];
    const int*   V_idx  = (const int*)d_in[1];
    const float* emb    = (const float*)d_in[2];
    const float* w_ih_f = (const float*)d_in[3];
    const float* w_hh_f = (const float*)d_in[4];
    const float* b_ih_f = (const float*)d_in[5];
    const float* b_hh_f = (const float*)d_in[6];
    const float* w_ih_b = (const float*)d_in[7];
    const float* w_hh_b = (const float*)d_in[8];
    const float* b_ih_b = (const float*)d_in[9];
    const float* b_hh_b = (const float*)d_in[10];
    const float* w1     = (const float*)d_in[11];
    const float* b1     = (const float*)d_in[12];
    const float* w2     = (const float*)d_in[13];
    const float* b2     = (const float*)d_in[14];
    const float* g1     = (const float*)d_in[15];
    const float* be1    = (const float*)d_in[16];
    const float* g2     = (const float*)d_in[17];
    const float* be2    = (const float*)d_in[18];

    float* ws = (float*)d_ws;
    float* out = (float*)d_out;

    // ---- workspace layout (float units); total ~207 MB (round-4 proven) ----
    float*    vsum   = ws;                               // 262144
    float*    vnorm  = ws + 262144;                      // 1024
    float*    mean   = ws + 263168;                      // 1024
    float*    istd   = ws + 264192;                      // 1024
    half2_t*  wqf    = (half2_t*)(ws + 265216);          // 98304 (chunked pack)
    half2_t*  wqb    = (half2_t*)(ws + 363520);          // 98304
    _Float16* vsh    = (_Float16*)(ws + 461824);         // 131072 fl
    _Float16* vsl    = (_Float16*)(ws + 592896);         // 131072 fl
    _Float16* wihh_f = (_Float16*)(ws + 723968);         // 98304 fl
    _Float16* wihl_f = (_Float16*)(ws + 822272);         // 98304 fl
    _Float16* wihh_b = (_Float16*)(ws + 920576);         // 98304 fl (f->b stride 393216 halves)
    _Float16* wihl_b = (_Float16*)(ws + 1018880);        // 98304 fl
    _Float16* w1h    = (_Float16*)(ws + 1117184);        // 65536 fl
    _Float16* w1l    = (_Float16*)(ws + 1182720);        // 65536 fl
    _Float16* w2h    = (_Float16*)(ws + 1248256);        // 65536 fl
    _Float16* w2l    = (_Float16*)(ws + 1313792);        // 65536 fl
    float*    AB     = ws + 1379328;                     // overlay arena
    _Float16* xeh    = (_Float16*)(AB + 0);              // st1-2
    _Float16* xel    = (_Float16*)(AB + 2097152);
    float*    gxf    = AB + 4194304;                     // st2-3 (f->b stride 12582912 fl)
    float*    gxb    = AB + 16777216;
    _Float16* dh     = (_Float16*)(AB + 29360128);       // st3-4 (+dtrans)
    _Float16* dl     = (_Float16*)(AB + 33554432);
    _Float16* dTh    = (_Float16*)(AB + 0);              // dtrans-st6 (xe/gx dead)
    _Float16* dTl    = (_Float16*)(AB + 4194304);
    float*    d2pre  = AB + 8388608;                     // st4 (gx dead)
    _Float16* d2h    = (_Float16*)(AB + 12582912);       // st4-5
    _Float16* d2l    = (_Float16*)(AB + 14680064);
    _Float16* ah     = (_Float16*)(AB + 16777216);       // st5-6 (gxb/d dead)
    _Float16* al     = (_Float16*)(AB + 25165824);
    _Float16* c16    = (_Float16*)(AB + 33554432);       // st6-7 (dl dead)
    float*    epre   = AB + 0;                           // st7-8 (dT/d2 dead)

    // Stage 1: gathers + packs
    vsum_kernel<<<Lz, 256, 0, stream>>>(V_idx, emb, vsum, vsh, vsl, vnorm);
    xe_kernel<<<Bz * Sz, 256, 0, stream>>>(x, emb, xeh, xel);
    wpack4_kernel<<<384, 256, 0, stream>>>(w_hh_f, w_hh_b, wqf, wqb);
    cvtsplit_kernel<<<768, 256, 0, stream>>>(w_ih_f, wihh_f, wihl_f, 196608);
    cvtsplit_kernel<<<768, 256, 0, stream>>>(w_ih_b, wihh_b, wihl_b, 196608);
    cvtsplit_kernel<<<512, 256, 0, stream>>>(w1, w1h, w1l, 131072);
    cvtsplit_kernel<<<512, 256, 0, stream>>>(w2, w2h, w2l, 131072);

    // Stage 2 (merged f+b via grid.z): gx = xe @ w_ih^T + b_ih  (M=16384, N=768, K=256)
    gemm_mfma<0, 1, 0, 1><<<dim3(6, 128, 2), 256, 0, stream>>>(
        xeh, xel, wihh_f, wihl_f, b_ih_f, b_ih_b, gxf, nullptr, nullptr,
        Bz * Sz, 768, Ez, 0, 393216, 12582912);

    // Stage 3: GRU (batch-paired) -> d hi/lo; transpose -> dT [B,512,256]
    gru_kernel<<<64, 512, 0, stream>>>(gxf, gxb, (const f16x8*)wqf, (const f16x8*)wqb,
                                       b_hh_f, b_hh_b, dh, dl);
    dtrans_kernel<<<dim3(4, 8, Bz), 256, 0, stream>>>(dh, dl, dTh, dTl);

    // Stage 4: d2pre = d @ w1^T + b1 (M=16384, N=256, K=512) f32; BN1+relu -> hi/lo
    gemm_mfma<0, 1, 0, 1><<<dim3(2, 128, 1), 256, 0, stream>>>(
        dh, dl, w1h, w1l, b1, b1, d2pre, nullptr, nullptr, Bz * Sz, Ez, 512, 0, 0, 0);
    bn_stats_kernel<<<Sz, 256, 0, stream>>>(d2pre, Sz, mean, istd);
    bn_apply_relu_kernel<<<Bz * Sz, 256, 0, stream>>>(d2pre, d2h, d2l, mean, istd, g1, be1);

    // Stage 5: a[b] = tanh(Vsum @ d2[b]^T)  (M=1024, N=256, K=256) -> hi/lo
    gemm_mfma<2, 0, 1, 1><<<dim3(2, 8, Bz), 256, 0, stream>>>(
        vsh, vsl, d2h, d2l, nullptr, nullptr, nullptr, ah, al,
        Lz, Sz, Ez, 0, (long)Sz * Ez, (long)Lz * Sz);

    // Stage 6: c[b] = relu(a[b] @ dT[b]^T)  (M=1024, N=512, K=256) -> hi only
    gemm_mfma<1, 0, 2, 1><<<dim3(4, 8, Bz), 256, 0, stream>>>(
        ah, al, dTh, dTl, nullptr, nullptr, nullptr, c16, nullptr, Lz, 512, Sz,
        (long)Lz * Sz, (long)512 * Sz, (long)Lz * 512);

    // Stage 7: epre = c @ w2^T + b2 (M=65536, N=256, K=512, A hi-only) f32; BN2 stats
    gemm_mfma<0, 1, 0, 0><<<dim3(2, 512, 1), 256, 0, stream>>>(
        c16, nullptr, w2h, w2l, b2, b2, epre, nullptr, nullptr, Bz * Lz, Ez, 512, 0, 0, 0);
    bn_stats_kernel<<<Lz, 256, 0, stream>>>(epre, Lz, mean, istd);

    // Stage 8: fused BN2-apply + tanh + cosine output
    bn_tanh_out_kernel<<<Bz * Lz, 256, 0, stream>>>(epre, mean, istd, g2, be2, vsum, vnorm, out);
}

// Round 12
// 665.729 us; speedup vs baseline: 1.3370x; 1.3370x over previous
//
#include <hip/hip_runtime.h>
#include <hip/hip_bf16.h>

// Sizes (fixed per problem)
#define Bz 64
#define Sz 256
#define Ez 256
#define Hz 256
#define Lz 1024
#define VLz 16

// split-precision scale: x stored as hi+lo of (x*SCL); products carry SCL^2
#define SCL 64.0f
#define DESCL (1.0f / 4096.0f)

typedef _Float16 half2_t __attribute__((ext_vector_type(2)));
typedef _Float16 half4_t __attribute__((ext_vector_type(4)));
typedef _Float16 f16x8   __attribute__((ext_vector_type(8)));
typedef float    f32x4   __attribute__((ext_vector_type(4)));

__device__ inline float fdot2(half2_t a, half2_t b, float c) {
#if __has_builtin(__builtin_amdgcn_fdot2)
    return __builtin_amdgcn_fdot2(a, b, c, false);
#else
    return c + (float)a[0] * (float)b[0] + (float)a[1] * (float)b[1];
#endif
}

// async global->LDS 16B; LDS dest must be linear lane-ordered (m104/m173)
__device__ inline void stage16(_Float16* ldst, const _Float16* gsrc) {
#if __has_builtin(__builtin_amdgcn_global_load_lds)
    __builtin_amdgcn_global_load_lds(
        (const __attribute__((address_space(1))) unsigned int*)gsrc,
        (__attribute__((address_space(3))) unsigned int*)ldst, 16, 0, 0);
#else
    *(f16x8*)ldst = *(const f16x8*)gsrc;
#endif
}

// ---------------------------------------------------------------------------
// K1: Vsum[l,e] = sum_j emb[V_idx[l,j], e]; norms; hi/lo split copy
__global__ void vsum_kernel(const int* __restrict__ V_idx, const float* __restrict__ emb,
                            float* __restrict__ Vsum, _Float16* __restrict__ vsh,
                            _Float16* __restrict__ vsl, float* __restrict__ vnorm)
{
    int l = blockIdx.x, e = threadIdx.x;
    float s = 0.f;
#pragma unroll
    for (int j = 0; j < VLz; ++j) {
        int idx = V_idx[l * VLz + j];
        s += emb[(long)idx * Ez + e];
    }
    Vsum[l * Ez + e] = s;
    float t = s * SCL;
    _Float16 h = (_Float16)t;
    vsh[l * Ez + e] = h;
    vsl[l * Ez + e] = (_Float16)(t - (float)h);
    __shared__ float red[256];
    red[e] = s * s; __syncthreads();
    for (int off = 128; off > 0; off >>= 1) { if (e < off) red[e] += red[e + off]; __syncthreads(); }
    if (e == 0) vnorm[l] = sqrtf(red[0]);
}

// K2: xe gather, hi/lo
__global__ void xe_kernel(const int* __restrict__ x, const float* __restrict__ emb,
                          _Float16* __restrict__ xeh, _Float16* __restrict__ xel)
{
    int i = blockIdx.x;              // b*S+s
    int e = threadIdx.x;
    float v = emb[(long)x[i] * Ez + e] * SCL;
    _Float16 h = (_Float16)v;
    xeh[(long)i * Ez + e] = h;
    xel[(long)i * Ez + e] = (_Float16)(v - (float)h);
}

// K3: pack w_hh [768,256] fp32 -> f16x2 quad layout for the GRU (round-2/4 proven).
// out index i = ((kq*3+g)*2+p)*256 + t  holds (w[g*256+t][4kq+2p], w[g*256+t][4kq+2p+1])
__global__ void wpack_kernel(const float* __restrict__ w_f, const float* __restrict__ w_b,
                             half2_t* __restrict__ out_f, half2_t* __restrict__ out_b)
{
    int i = blockIdx.x * 256 + threadIdx.x;   // 0 .. 98303
    int t = i & 255;
    int rest = i >> 8;          // (kq*3+g)*2+p
    int p = rest & 1;
    int gq = rest >> 1;
    int g = gq % 3;
    int kq = gq / 3;
    int o = g * 256 + t;
    int k = 4 * kq + 2 * p;
    out_f[i] = half2_t{(_Float16)w_f[o * 256 + k], (_Float16)w_f[o * 256 + k + 1]};
    out_b[i] = half2_t{(_Float16)w_b[o * 256 + k], (_Float16)w_b[o * 256 + k + 1]};
}

// f32 -> scaled hi/lo f16
__global__ void cvtsplit_kernel(const float* __restrict__ in, _Float16* __restrict__ hi,
                                _Float16* __restrict__ lo, int n)
{
    int i = blockIdx.x * 256 + threadIdx.x;
    if (i < n) {
        float v = in[i] * SCL;
        _Float16 h = (_Float16)v;
        hi[i] = h;
        lo[i] = (_Float16)(v - (float)h);
    }
}

// ---------------------------------------------------------------------------
// Split-precision MFMA NT GEMM (round-4 proven): C = (1/4096)*(Ah+Al)@(Bh+Bl)^T.
// acc = Ah*Bh + Ah*Bl (+ Al*Bh if SPLIT_A). BM=BN=128, BK=32, 4 waves 2x2.
// OUTM: 0 = f32 C, 1 = scaled hi/lo f16 (Ch,Cl), 2 = scaled hi f16 only.
// bias_b: alternate bias selected when blockIdx.z==1 (merged f/b dispatches).
template<int EPI, int BIAS, int OUTM, int SPLIT_A>
__global__ __launch_bounds__(256, 2) void gemm_mfma(
    const _Float16* __restrict__ Ah, const _Float16* __restrict__ Al,
    const _Float16* __restrict__ Bh, const _Float16* __restrict__ Bl,
    const float* __restrict__ bias, const float* __restrict__ bias_b,
    float* __restrict__ C, _Float16* __restrict__ Ch, _Float16* __restrict__ Cl,
    int M, int N, int K, long sA, long sB, long sC)
{
    int bz = blockIdx.z;
    Ah += (long)bz * sA;
    if (SPLIT_A) Al += (long)bz * sA;
    Bh += (long)bz * sB;
    Bl += (long)bz * sB;
    const float* bp = BIAS ? (bz ? bias_b : bias) : nullptr;
    __shared__ __attribute__((aligned(16))) _Float16 Ash[128 * 32];
    __shared__ __attribute__((aligned(16))) _Float16 Asl[128 * 32];
    __shared__ __attribute__((aligned(16))) _Float16 Bsh[128 * 32];
    __shared__ __attribute__((aligned(16))) _Float16 Bsl[128 * 32];
    int tid = threadIdx.x;
    int lane = tid & 63;
    int wid = tid >> 6;
    int wm = wid >> 1, wn = wid & 1;
    int m0 = blockIdx.y * 128, n0 = blockIdx.x * 128;

    int srow = tid >> 2, sslot = tid & 3;
    int sw0 = sslot ^ ((srow >> 1) & 3);
    long a0 = (long)(m0 + srow) * K + sw0 * 8;
    long a1 = (long)(m0 + 64 + srow) * K + sw0 * 8;
    long b0 = (long)(n0 + srow) * K + sw0 * 8;
    long b1 = (long)(n0 + 64 + srow) * K + sw0 * 8;

    f32x4 acc[4][4] = {};
    int r16 = lane & 15, kg = lane >> 4;

    for (int k0 = 0; k0 < K; k0 += 32) {
        stage16(&Ash[tid * 8],        Ah + a0 + k0);
        stage16(&Ash[2048 + tid * 8], Ah + a1 + k0);
        if (SPLIT_A) {
            stage16(&Asl[tid * 8],        Al + a0 + k0);
            stage16(&Asl[2048 + tid * 8], Al + a1 + k0);
        }
        stage16(&Bsh[tid * 8],        Bh + b0 + k0);
        stage16(&Bsh[2048 + tid * 8], Bh + b1 + k0);
        stage16(&Bsl[tid * 8],        Bl + b0 + k0);
        stage16(&Bsl[2048 + tid * 8], Bl + b1 + k0);
        __syncthreads();
        f16x8 afh[4], afl[4], bfh[4], bfl[4];
#pragma unroll
        for (int mi = 0; mi < 4; ++mi) {
            int r = wm * 64 + mi * 16 + r16;
            int sl = kg ^ ((r >> 1) & 3);
            int off = r * 32 + sl * 8;
            afh[mi] = *(const f16x8*)&Ash[off];
            if (SPLIT_A) afl[mi] = *(const f16x8*)&Asl[off];
        }
#pragma unroll
        for (int ni = 0; ni < 4; ++ni) {
            int n = wn * 64 + ni * 16 + r16;
            int sl = kg ^ ((n >> 1) & 3);
            int off = n * 32 + sl * 8;
            bfh[ni] = *(const f16x8*)&Bsh[off];
            bfl[ni] = *(const f16x8*)&Bsl[off];
        }
#pragma unroll
        for (int mi = 0; mi < 4; ++mi)
#pragma unroll
            for (int ni = 0; ni < 4; ++ni) {
                acc[mi][ni] = __builtin_amdgcn_mfma_f32_16x16x32_f16(afh[mi], bfh[ni], acc[mi][ni], 0, 0, 0);
                acc[mi][ni] = __builtin_amdgcn_mfma_f32_16x16x32_f16(afh[mi], bfl[ni], acc[mi][ni], 0, 0, 0);
                if (SPLIT_A)
                    acc[mi][ni] = __builtin_amdgcn_mfma_f32_16x16x32_f16(afl[mi], bfh[ni], acc[mi][ni], 0, 0, 0);
            }
        __syncthreads();
    }

    long coff = (long)bz * sC;
#pragma unroll
    for (int mi = 0; mi < 4; ++mi) {
#pragma unroll
        for (int ni = 0; ni < 4; ++ni) {
            int n = n0 + wn * 64 + ni * 16 + r16;
            float bv = BIAS ? bp[n] : 0.f;
#pragma unroll
            for (int j = 0; j < 4; ++j) {
                int m = m0 + wm * 64 + mi * 16 + kg * 4 + j;
                float v = acc[mi][ni][j] * DESCL + bv;
                if (EPI == 1) v = fmaxf(v, 0.f);
                if (EPI == 2) v = tanhf(v);
                long idx = coff + (long)m * N + n;
                if (OUTM == 0) {
                    C[idx] = v;
                } else if (OUTM == 1) {
                    float t = v * SCL;
                    _Float16 h = (_Float16)t;
                    Ch[idx] = h;
                    Cl[idx] = (_Float16)(t - (float)h);
                } else {
                    Ch[idx] = (_Float16)(v * SCL);
                }
            }
        }
    }
}

// ---------------------------------------------------------------------------
// K4: GRU recurrence — round-4/10 exact. 361us, measured AT the 35.7 TB/s
// aggregate L2 ceiling (128 blocks x 393KB x 256 steps / 361us). Structural
// roofline: recurrence forbids t- or k-splits across blocks (full h needed
// each step) -> grid capped at 128 = dir x batch; all sharing variants
// measured worse (r5 pin, r6 Q=1, r7 MFMA, r9 LDS-hybrid, r11 batch-pair).
__global__ __launch_bounds__(512, 2) void gru_kernel(
    const float* __restrict__ gx_f, const float* __restrict__ gx_b,
    const half2_t* __restrict__ wq_f, const half2_t* __restrict__ wq_b,
    const float* __restrict__ bhh_f, const float* __restrict__ bhh_b,
    _Float16* __restrict__ dh_out, _Float16* __restrict__ dl_out)
{
    int dir = blockIdx.x >> 6;
    int b   = blockIdx.x & 63;
    const float*   gx  = dir ? gx_b : gx_f;
    const half2_t* wq  = dir ? wq_b : wq_f;
    const float*   bhh = dir ? bhh_b : bhh_f;
    int tid = threadIdx.x;
    int t = tid & 255, q = tid >> 8;

    __shared__ __attribute__((aligned(16))) _Float16 hbuf[256];
    __shared__ float hf32[256];
    __shared__ float part[2 * 768];

    half2_t wr[192];
    const half2_t* wbase = wq + (size_t)q * 192 * 256 + t;
#pragma unroll
    for (int m = 0; m < 192; ++m) wr[m] = wbase[m << 8];

    float br = 0.f, bz = 0.f, bn = 0.f, hprev = 0.f;
    if (q == 0) {
        br = bhh[t]; bz = bhh[256 + t]; bn = bhh[512 + t];
        hbuf[t] = (_Float16)0.f;
        hf32[t] = 0.f;
    }
    __syncthreads();

    for (int step = 0; step < Sz; ++step) {
        int s = dir ? (Sz - 1 - step) : step;
        // deferred previous-step d write (overlaps dot phase)
        if (q == 1 && step > 0) {
            int sp = dir ? (Sz - step) : (step - 1);
            float hv = hf32[t] * SCL;
            _Float16 hh = (_Float16)hv;
            size_t idx = (size_t)(b * Sz + sp) * 512 + dir * 256 + t;
            dh_out[idx] = hh;
            dl_out[idx] = (_Float16)(hv - (float)hh);
        }
        const float* g = gx + (size_t)(b * Sz + s) * 768;
        float xr = 0.f, xz = 0.f, xn = 0.f;
        if (q == 0) { xr = g[t]; xz = g[256 + t]; xn = g[512 + t]; }

        float ar = 0.f, az = 0.f, an = 0.f;
        const half4_t* hp = (const half4_t*)hbuf;
#pragma unroll
        for (int jj = 0; jj < 32; ++jj) {
            half4_t hv = hp[q * 32 + jj];
            half2_t h01 = {hv[0], hv[1]};
            half2_t h23 = {hv[2], hv[3]};
            ar = fdot2(wr[jj * 6 + 0], h01, ar); ar = fdot2(wr[jj * 6 + 1], h23, ar);
            az = fdot2(wr[jj * 6 + 2], h01, az); az = fdot2(wr[jj * 6 + 3], h23, az);
            an = fdot2(wr[jj * 6 + 4], h01, an); an = fdot2(wr[jj * 6 + 5], h23, an);
        }
        part[q * 768 + t]       = ar;
        part[q * 768 + 256 + t] = az;
        part[q * 768 + 512 + t] = an;
        __syncthreads();

        if (q == 0) {
            float hr = part[t]       + part[768 + t];
            float hz = part[256 + t] + part[768 + 256 + t];
            float hn = part[512 + t] + part[768 + 512 + t];
            float r  = 1.f / (1.f + expf(-(xr + br + hr)));
            float z  = 1.f / (1.f + expf(-(xz + bz + hz)));
            float nn = tanhf(xn + r * (hn + bn));
            hprev = (1.f - z) * nn + z * hprev;
            hbuf[t] = (_Float16)hprev;
            hf32[t] = hprev;
        }
        __syncthreads();
    }
    // final step's d write
    if (q == 1) {
        int sl = dir ? 0 : (Sz - 1);
        float hv = hf32[t] * SCL;
        _Float16 hh = (_Float16)hv;
        size_t idx = (size_t)(b * Sz + sl) * 512 + dir * 256 + t;
        dh_out[idx] = hh;
        dl_out[idx] = (_Float16)(hv - (float)hh);
    }
}

// ---------------------------------------------------------------------------
// transpose d (hi,lo) [B*S][512] -> dT (hi,lo) [B][512][256]
__global__ __launch_bounds__(256) void dtrans_kernel(
    const _Float16* __restrict__ dh, const _Float16* __restrict__ dl,
    _Float16* __restrict__ dTh, _Float16* __restrict__ dTl)
{
    __shared__ _Float16 th[64][68];
    __shared__ _Float16 tl[64][68];
    int s0 = blockIdx.x << 6;
    int h0 = blockIdx.y << 6;
    int b  = blockIdx.z;
    int tid = threadIdx.x;
#pragma unroll
    for (int i = 0; i < 16; ++i) {
        int idx = tid + i * 256;
        int s = idx >> 6, h = idx & 63;
        size_t gi = (size_t)(b * 256 + s0 + s) * 512 + h0 + h;
        th[s][h] = dh[gi];
        tl[s][h] = dl[gi];
    }
    __syncthreads();
#pragma unroll
    for (int i = 0; i < 16; ++i) {
        int idx = tid + i * 256;
        int h = idx >> 6, s = idx & 63;
        size_t gi = (size_t)(b * 512 + h0 + h) * 256 + s0 + s;
        dTh[gi] = th[s][h];
        dTl[gi] = tl[s][h];
    }
}

// ---------------------------------------------------------------------------
// BN stats over (b, e) for each channel c (layout y[b][CH][256])
__global__ void bn_stats_kernel(const float* __restrict__ y, int CH,
                                float* __restrict__ mean, float* __restrict__ istd)
{
    int c = blockIdx.x, t = threadIdx.x;
    float s = 0.f, ss = 0.f;
    for (int b = 0; b < Bz; ++b) {
        float v = y[((long)b * CH + c) * 256 + t];
        s += v; ss += v * v;
    }
    __shared__ float rs[256], rss[256];
    rs[t] = s; rss[t] = ss; __syncthreads();
    for (int off = 128; off > 0; off >>= 1) {
        if (t < off) { rs[t] += rs[t + off]; rss[t] += rss[t + off]; }
        __syncthreads();
    }
    if (t == 0) {
        float cnt = (float)(Bz * 256);
        float m = rs[0] / cnt;
        float var = rss[0] / cnt - m * m;
        mean[c] = m;
        istd[c] = rsqrtf(var + 1e-5f);
    }
}

// BN1 apply + relu -> scaled hi/lo f16
__global__ void bn_apply_relu_kernel(const float* __restrict__ y,
                                     _Float16* __restrict__ yh, _Float16* __restrict__ yl,
                                     const float* __restrict__ mean, const float* __restrict__ istd,
                                     const float* __restrict__ g, const float* __restrict__ be)
{
    long i = (long)blockIdx.x * 256 + threadIdx.x;
    int c = (int)((i >> 8) % Sz);
    float v = (y[i] - mean[c]) * istd[c] * g[c] + be[c];
    v = fmaxf(v, 0.f);
    float t = v * SCL;
    _Float16 h = (_Float16)t;
    yh[i] = h;
    yl[i] = (_Float16)(t - (float)h);
}

// ---------------------------------------------------------------------------
// Fused BN2-apply + tanh + cosine-similarity output
__global__ void bn_tanh_out_kernel(const float* __restrict__ epre,
                                   const float* __restrict__ mean, const float* __restrict__ istd,
                                   const float* __restrict__ g, const float* __restrict__ be,
                                   const float* __restrict__ Vsum, const float* __restrict__ vnorm,
                                   float* __restrict__ out)
{
    int bl = blockIdx.x;               // b*Lz + l
    int l = bl & (Lz - 1);
    int t = threadIdx.x;
    float v = (epre[(long)bl * 256 + t] - mean[l]) * istd[l] * g[l] + be[l];
    float ev = tanhf(v);
    float vv = Vsum[l * 256 + t];
    __shared__ float rd[256], rn[256];
    rd[t] = ev * vv; rn[t] = ev * ev; __syncthreads();
    for (int off = 128; off > 0; off >>= 1) {
        if (t < off) { rd[t] += rd[t + off]; rn[t] += rn[t + off]; }
        __syncthreads();
    }
    if (t == 0) {
        float num = rd[0];
        float den = fmaxf(sqrtf(rn[0]), 1e-8f) * fmaxf(vnorm[l], 1e-8f);
        out[bl] = num / den * 10.f;
    }
}

// ---------------------------------------------------------------------------
extern "C" void kernel_launch(void* const* d_in, const int* in_sizes, int n_in,
                              void* d_out, int out_size, void* d_ws, size_t ws_size,
                              hipStream_t stream)
{
    const int*   x      = (const int*)d_in[0];
    const int*   V_idx  = (const int*)d_in[1];
    const float* emb    = (const float*)d_in[2];
    const float* w_ih_f = (const float*)d_in[3];
    const float* w_hh_f = (const float*)d_in[4];
    const float* b_ih_f = (const float*)d_in[5];
    const float* b_hh_f = (const float*)d_in[6];
    const float* w_ih_b = (const float*)d_in[7];
    const float* w_hh_b = (const float*)d_in[8];
    const float* b_ih_b = (const float*)d_in[9];
    const float* b_hh_b = (const float*)d_in[10];
    const float* w1     = (const float*)d_in[11];
    const float* b1     = (const float*)d_in[12];
    const float* w2     = (const float*)d_in[13];
    const float* b2     = (const float*)d_in[14];
    const float* g1     = (const float*)d_in[15];
    const float* be1    = (const float*)d_in[16];
    const float* g2     = (const float*)d_in[17];
    const float* be2    = (const float*)d_in[18];

    float* ws = (float*)d_ws;
    float* out = (float*)d_out;

    // ---- workspace layout (float units); total ~207 MB (round-4 proven) ----
    float*    vsum   = ws;                               // 262144
    float*    vnorm  = ws + 262144;                      // 1024
    float*    mean   = ws + 263168;                      // 1024
    float*    istd   = ws + 264192;                      // 1024
    half2_t*  wqf    = (half2_t*)(ws + 265216);          // 98304
    half2_t*  wqb    = (half2_t*)(ws + 363520);          // 98304
    _Float16* vsh    = (_Float16*)(ws + 461824);         // 131072 fl
    _Float16* vsl    = (_Float16*)(ws + 592896);         // 131072 fl
    _Float16* wihh_f = (_Float16*)(ws + 723968);         // 98304 fl
    _Float16* wihl_f = (_Float16*)(ws + 822272);         // 98304 fl
    _Float16* wihh_b = (_Float16*)(ws + 920576);         // 98304 fl (f->b stride 393216 halves)
    _Float16* wihl_b = (_Float16*)(ws + 1018880);        // 98304 fl
    _Float16* w1h    = (_Float16*)(ws + 1117184);        // 65536 fl
    _Float16* w1l    = (_Float16*)(ws + 1182720);        // 65536 fl
    _Float16* w2h    = (_Float16*)(ws + 1248256);        // 65536 fl
    _Float16* w2l    = (_Float16*)(ws + 1313792);        // 65536 fl
    float*    AB     = ws + 1379328;                     // overlay arena
    _Float16* xeh    = (_Float16*)(AB + 0);              // st1-2
    _Float16* xel    = (_Float16*)(AB + 2097152);
    float*    gxf    = AB + 4194304;                     // st2-3 (f->b stride 12582912 fl)
    float*    gxb    = AB + 16777216;
    _Float16* dh     = (_Float16*)(AB + 29360128);       // st3-4 (+dtrans)
    _Float16* dl     = (_Float16*)(AB + 33554432);
    _Float16* dTh    = (_Float16*)(AB + 0);              // dtrans-st6 (xe/gx dead)
    _Float16* dTl    = (_Float16*)(AB + 4194304);
    float*    d2pre  = AB + 8388608;                     // st4 (gx dead)
    _Float16* d2h    = (_Float16*)(AB + 12582912);       // st4-5
    _Float16* d2l    = (_Float16*)(AB + 14680064);
    _Float16* ah     = (_Float16*)(AB + 16777216);       // st5-6 (gxb/d dead)
    _Float16* c16    = (_Float16*)(AB + 33554432);       // st6-7 (dl dead)
    float*    epre   = AB + 0;                           // st7-8 (dT/d2 dead)

    // Stage 1: gathers + packs
    vsum_kernel<<<Lz, 256, 0, stream>>>(V_idx, emb, vsum, vsh, vsl, vnorm);
    xe_kernel<<<Bz * Sz, 256, 0, stream>>>(x, emb, xeh, xel);
    wpack_kernel<<<384, 256, 0, stream>>>(w_hh_f, w_hh_b, wqf, wqb);
    cvtsplit_kernel<<<768, 256, 0, stream>>>(w_ih_f, wihh_f, wihl_f, 196608);
    cvtsplit_kernel<<<768, 256, 0, stream>>>(w_ih_b, wihh_b, wihl_b, 196608);
    cvtsplit_kernel<<<512, 256, 0, stream>>>(w1, w1h, w1l, 131072);
    cvtsplit_kernel<<<512, 256, 0, stream>>>(w2, w2h, w2l, 131072);

    // Stage 2 (merged f+b via grid.z): gx = xe @ w_ih^T + b_ih  (M=16384, N=768, K=256)
    gemm_mfma<0, 1, 0, 1><<<dim3(6, 128, 2), 256, 0, stream>>>(
        xeh, xel, wihh_f, wihl_f, b_ih_f, b_ih_b, gxf, nullptr, nullptr,
        Bz * Sz, 768, Ez, 0, 393216, 12582912);

    // Stage 3: GRU (round-4 exact) -> d hi/lo; transpose -> dT [B,512,256]
    gru_kernel<<<128, 512, 0, stream>>>(gxf, gxb, wqf, wqb, b_hh_f, b_hh_b, dh, dl);
    dtrans_kernel<<<dim3(4, 8, Bz), 256, 0, stream>>>(dh, dl, dTh, dTl);

    // Stage 4: d2pre = d @ w1^T + b1 (M=16384, N=256, K=512) f32; BN1+relu -> hi/lo
    gemm_mfma<0, 1, 0, 1><<<dim3(2, 128, 1), 256, 0, stream>>>(
        dh, dl, w1h, w1l, b1, b1, d2pre, nullptr, nullptr, Bz * Sz, Ez, 512, 0, 0, 0);
    bn_stats_kernel<<<Sz, 256, 0, stream>>>(d2pre, Sz, mean, istd);
    bn_apply_relu_kernel<<<Bz * Sz, 256, 0, stream>>>(d2pre, d2h, d2l, mean, istd, g1, be1);

    // Stage 5: a[b] = tanh(Vsum @ d2[b]^T)  (M=1024, N=256, K=256) -> hi only
    // (this round's single lever, part 1: a stored hi-only; a is a tanh output,
    //  |a|<=1, f16 relative error 2^-11 — feedforward splits measured ~0
    //  contribution to absmax in r2-vs-r4)
    gemm_mfma<2, 0, 2, 1><<<dim3(2, 8, Bz), 256, 0, stream>>>(
        vsh, vsl, d2h, d2l, nullptr, nullptr, nullptr, ah, nullptr,
        Lz, Sz, Ez, 0, (long)Sz * Ez, (long)Lz * Sz);

    // Stage 6: c[b] = relu(a[b] @ dT[b]^T)  (M=1024, N=512, K=256), A hi-only
    // (lever part 2: SPLIT_A=0 -> 3 MFMA passes -> 2; B keeps d hi/lo)
    gemm_mfma<1, 0, 2, 0><<<dim3(4, 8, Bz), 256, 0, stream>>>(
        ah, nullptr, dTh, dTl, nullptr, nullptr, nullptr, c16, nullptr, Lz, 512, Sz,
        (long)Lz * Sz, (long)512 * Sz, (long)Lz * 512);

    // Stage 7: epre = c @ w2^T + b2 (M=65536, N=256, K=512, A hi-only) f32; BN2 stats
    gemm_mfma<0, 1, 0, 0><<<dim3(2, 512, 1), 256, 0, stream>>>(
        c16, nullptr, w2h, w2l, b2, b2, epre, nullptr, nullptr, Bz * Lz, Ez, 512, 0, 0, 0);
    bn_stats_kernel<<<Lz, 256, 0, stream>>>(epre, Lz, mean, istd);

    // Stage 8: fused BN2-apply + tanh + cosine output
    bn_tanh_out_kernel<<<Bz * Lz, 256, 0, stream>>>(epre, mean, istd, g2, be2, vsum, vnorm, out);
}

// Round 13
// 648.282 us; speedup vs baseline: 1.3730x; 1.0269x over previous
//
#include <hip/hip_runtime.h>
#include <hip/hip_bf16.h>

// Sizes (fixed per problem)
#define Bz 64
#define Sz 256
#define Ez 256
#define Hz 256
#define Lz 1024
#define VLz 16

// split-precision scale: x stored as hi+lo of (x*SCL); products carry SCL^2
#define SCL 64.0f
#define DESCL (1.0f / 4096.0f)

typedef _Float16 half2_t __attribute__((ext_vector_type(2)));
typedef _Float16 half4_t __attribute__((ext_vector_type(4)));
typedef _Float16 f16x8   __attribute__((ext_vector_type(8)));
typedef float    f32x4   __attribute__((ext_vector_type(4)));

__device__ inline float fdot2(half2_t a, half2_t b, float c) {
#if __has_builtin(__builtin_amdgcn_fdot2)
    return __builtin_amdgcn_fdot2(a, b, c, false);
#else
    return c + (float)a[0] * (float)b[0] + (float)a[1] * (float)b[1];
#endif
}

// async global->LDS 16B; LDS dest must be linear lane-ordered (m104/m173)
__device__ inline void stage16(_Float16* ldst, const _Float16* gsrc) {
#if __has_builtin(__builtin_amdgcn_global_load_lds)
    __builtin_amdgcn_global_load_lds(
        (const __attribute__((address_space(1))) unsigned int*)gsrc,
        (__attribute__((address_space(3))) unsigned int*)ldst, 16, 0, 0);
#else
    *(f16x8*)ldst = *(const f16x8*)gsrc;
#endif
}

// ---------------------------------------------------------------------------
// K1: Vsum[l,e] = sum_j emb[V_idx[l,j], e]; norms; hi/lo split copy
// (vsum-lo is LOAD-BEARING: r8-vs-r12 isolated its drop to +0.03 absmax)
__global__ void vsum_kernel(const int* __restrict__ V_idx, const float* __restrict__ emb,
                            float* __restrict__ Vsum, _Float16* __restrict__ vsh,
                            _Float16* __restrict__ vsl, float* __restrict__ vnorm)
{
    int l = blockIdx.x, e = threadIdx.x;
    float s = 0.f;
#pragma unroll
    for (int j = 0; j < VLz; ++j) {
        int idx = V_idx[l * VLz + j];
        s += emb[(long)idx * Ez + e];
    }
    Vsum[l * Ez + e] = s;
    float t = s * SCL;
    _Float16 h = (_Float16)t;
    vsh[l * Ez + e] = h;
    vsl[l * Ez + e] = (_Float16)(t - (float)h);
    __shared__ float red[256];
    red[e] = s * s; __syncthreads();
    for (int off = 128; off > 0; off >>= 1) { if (e < off) red[e] += red[e + off]; __syncthreads(); }
    if (e == 0) vnorm[l] = sqrtf(red[0]);
}

// K2: xe gather, hi/lo
__global__ void xe_kernel(const int* __restrict__ x, const float* __restrict__ emb,
                          _Float16* __restrict__ xeh, _Float16* __restrict__ xel)
{
    int i = blockIdx.x;              // b*S+s
    int e = threadIdx.x;
    float v = emb[(long)x[i] * Ez + e] * SCL;
    _Float16 h = (_Float16)v;
    xeh[(long)i * Ez + e] = h;
    xel[(long)i * Ez + e] = (_Float16)(v - (float)h);
}

// K3: pack w_hh [768,256] fp32 -> f16x2 quad layout for the GRU (round-2/4 proven).
__global__ void wpack_kernel(const float* __restrict__ w_f, const float* __restrict__ w_b,
                             half2_t* __restrict__ out_f, half2_t* __restrict__ out_b)
{
    int i = blockIdx.x * 256 + threadIdx.x;   // 0 .. 98303
    int t = i & 255;
    int rest = i >> 8;          // (kq*3+g)*2+p
    int p = rest & 1;
    int gq = rest >> 1;
    int g = gq % 3;
    int kq = gq / 3;
    int o = g * 256 + t;
    int k = 4 * kq + 2 * p;
    out_f[i] = half2_t{(_Float16)w_f[o * 256 + k], (_Float16)w_f[o * 256 + k + 1]};
    out_b[i] = half2_t{(_Float16)w_b[o * 256 + k], (_Float16)w_b[o * 256 + k + 1]};
}

// f32 -> scaled hi/lo f16
__global__ void cvtsplit_kernel(const float* __restrict__ in, _Float16* __restrict__ hi,
                                _Float16* __restrict__ lo, int n)
{
    int i = blockIdx.x * 256 + threadIdx.x;
    if (i < n) {
        float v = in[i] * SCL;
        _Float16 h = (_Float16)v;
        hi[i] = h;
        lo[i] = (_Float16)(v - (float)h);
    }
}

// ---------------------------------------------------------------------------
// Split-precision MFMA NT GEMM: C = (1/4096)*(Ah[+Al])@(Bh[+Bl])^T (+bias)(+epi).
// acc = Ah*Bh (+ Ah*Bl if SPLIT_B) (+ Al*Bh if SPLIT_A). BM=BN=128, BK=32.
// OUTM: 0 = f32 C, 1 = scaled hi/lo f16 (Ch,Cl), 2 = scaled hi f16 only.
// bias_b: alternate bias selected when blockIdx.z==1 (merged f/b dispatches).
template<int EPI, int BIAS, int OUTM, int SPLIT_A, int SPLIT_B>
__global__ __launch_bounds__(256, 2) void gemm_mfma(
    const _Float16* __restrict__ Ah, const _Float16* __restrict__ Al,
    const _Float16* __restrict__ Bh, const _Float16* __restrict__ Bl,
    const float* __restrict__ bias, const float* __restrict__ bias_b,
    float* __restrict__ C, _Float16* __restrict__ Ch, _Float16* __restrict__ Cl,
    int M, int N, int K, long sA, long sB, long sC)
{
    int bz = blockIdx.z;
    Ah += (long)bz * sA;
    if (SPLIT_A) Al += (long)bz * sA;
    Bh += (long)bz * sB;
    if (SPLIT_B) Bl += (long)bz * sB;
    const float* bp = BIAS ? (bz ? bias_b : bias) : nullptr;
    __shared__ __attribute__((aligned(16))) _Float16 Ash[128 * 32];
    __shared__ __attribute__((aligned(16))) _Float16 Asl[128 * 32];
    __shared__ __attribute__((aligned(16))) _Float16 Bsh[128 * 32];
    __shared__ __attribute__((aligned(16))) _Float16 Bsl[128 * 32];
    int tid = threadIdx.x;
    int lane = tid & 63;
    int wid = tid >> 6;
    int wm = wid >> 1, wn = wid & 1;
    int m0 = blockIdx.y * 128, n0 = blockIdx.x * 128;

    int srow = tid >> 2, sslot = tid & 3;
    int sw0 = sslot ^ ((srow >> 1) & 3);
    long a0 = (long)(m0 + srow) * K + sw0 * 8;
    long a1 = (long)(m0 + 64 + srow) * K + sw0 * 8;
    long b0 = (long)(n0 + srow) * K + sw0 * 8;
    long b1 = (long)(n0 + 64 + srow) * K + sw0 * 8;

    f32x4 acc[4][4] = {};
    int r16 = lane & 15, kg = lane >> 4;

    for (int k0 = 0; k0 < K; k0 += 32) {
        stage16(&Ash[tid * 8],        Ah + a0 + k0);
        stage16(&Ash[2048 + tid * 8], Ah + a1 + k0);
        if (SPLIT_A) {
            stage16(&Asl[tid * 8],        Al + a0 + k0);
            stage16(&Asl[2048 + tid * 8], Al + a1 + k0);
        }
        stage16(&Bsh[tid * 8],        Bh + b0 + k0);
        stage16(&Bsh[2048 + tid * 8], Bh + b1 + k0);
        if (SPLIT_B) {
            stage16(&Bsl[tid * 8],        Bl + b0 + k0);
            stage16(&Bsl[2048 + tid * 8], Bl + b1 + k0);
        }
        __syncthreads();
        f16x8 afh[4], afl[4], bfh[4], bfl[4];
#pragma unroll
        for (int mi = 0; mi < 4; ++mi) {
            int r = wm * 64 + mi * 16 + r16;
            int sl = kg ^ ((r >> 1) & 3);
            int off = r * 32 + sl * 8;
            afh[mi] = *(const f16x8*)&Ash[off];
            if (SPLIT_A) afl[mi] = *(const f16x8*)&Asl[off];
        }
#pragma unroll
        for (int ni = 0; ni < 4; ++ni) {
            int n = wn * 64 + ni * 16 + r16;
            int sl = kg ^ ((n >> 1) & 3);
            int off = n * 32 + sl * 8;
            bfh[ni] = *(const f16x8*)&Bsh[off];
            if (SPLIT_B) bfl[ni] = *(const f16x8*)&Bsl[off];
        }
#pragma unroll
        for (int mi = 0; mi < 4; ++mi)
#pragma unroll
            for (int ni = 0; ni < 4; ++ni) {
                acc[mi][ni] = __builtin_amdgcn_mfma_f32_16x16x32_f16(afh[mi], bfh[ni], acc[mi][ni], 0, 0, 0);
                if (SPLIT_B)
                    acc[mi][ni] = __builtin_amdgcn_mfma_f32_16x16x32_f16(afh[mi], bfl[ni], acc[mi][ni], 0, 0, 0);
                if (SPLIT_A)
                    acc[mi][ni] = __builtin_amdgcn_mfma_f32_16x16x32_f16(afl[mi], bfh[ni], acc[mi][ni], 0, 0, 0);
            }
        __syncthreads();
    }

    long coff = (long)bz * sC;
#pragma unroll
    for (int mi = 0; mi < 4; ++mi) {
#pragma unroll
        for (int ni = 0; ni < 4; ++ni) {
            int n = n0 + wn * 64 + ni * 16 + r16;
            float bv = BIAS ? bp[n] : 0.f;
#pragma unroll
            for (int j = 0; j < 4; ++j) {
                int m = m0 + wm * 64 + mi * 16 + kg * 4 + j;
                float v = acc[mi][ni][j] * DESCL + bv;
                if (EPI == 1) v = fmaxf(v, 0.f);
                if (EPI == 2) v = tanhf(v);
                long idx = coff + (long)m * N + n;
                if (OUTM == 0) {
                    C[idx] = v;
                } else if (OUTM == 1) {
                    float t = v * SCL;
                    _Float16 h = (_Float16)t;
                    Ch[idx] = h;
                    Cl[idx] = (_Float16)(t - (float)h);
                } else {
                    Ch[idx] = (_Float16)(v * SCL);
                }
            }
        }
    }
}

// ---------------------------------------------------------------------------
// K4: GRU recurrence — round-4/10 exact. 361us, measured AT the 35.7 TB/s
// aggregate L2 ceiling (128 blocks x 393KB x 256 steps / 361us). Structural
// roofline: recurrence forbids t- or k-splits across blocks (full h needed
// each step) -> grid capped at 128 = dir x batch; all sharing variants
// measured worse (r5 pin, r6 Q=1, r7 MFMA, r9 LDS-hybrid, r11 batch-pair).
__global__ __launch_bounds__(512, 2) void gru_kernel(
    const float* __restrict__ gx_f, const float* __restrict__ gx_b,
    const half2_t* __restrict__ wq_f, const half2_t* __restrict__ wq_b,
    const float* __restrict__ bhh_f, const float* __restrict__ bhh_b,
    _Float16* __restrict__ dh_out, _Float16* __restrict__ dl_out)
{
    int dir = blockIdx.x >> 6;
    int b   = blockIdx.x & 63;
    const float*   gx  = dir ? gx_b : gx_f;
    const half2_t* wq  = dir ? wq_b : wq_f;
    const float*   bhh = dir ? bhh_b : bhh_f;
    int tid = threadIdx.x;
    int t = tid & 255, q = tid >> 8;

    __shared__ __attribute__((aligned(16))) _Float16 hbuf[256];
    __shared__ float hf32[256];
    __shared__ float part[2 * 768];

    half2_t wr[192];
    const half2_t* wbase = wq + (size_t)q * 192 * 256 + t;
#pragma unroll
    for (int m = 0; m < 192; ++m) wr[m] = wbase[m << 8];

    float br = 0.f, bz = 0.f, bn = 0.f, hprev = 0.f;
    if (q == 0) {
        br = bhh[t]; bz = bhh[256 + t]; bn = bhh[512 + t];
        hbuf[t] = (_Float16)0.f;
        hf32[t] = 0.f;
    }
    __syncthreads();

    for (int step = 0; step < Sz; ++step) {
        int s = dir ? (Sz - 1 - step) : step;
        // deferred previous-step d write (overlaps dot phase)
        if (q == 1 && step > 0) {
            int sp = dir ? (Sz - step) : (step - 1);
            float hv = hf32[t] * SCL;
            _Float16 hh = (_Float16)hv;
            size_t idx = (size_t)(b * Sz + sp) * 512 + dir * 256 + t;
            dh_out[idx] = hh;
            dl_out[idx] = (_Float16)(hv - (float)hh);
        }
        const float* g = gx + (size_t)(b * Sz + s) * 768;
        float xr = 0.f, xz = 0.f, xn = 0.f;
        if (q == 0) { xr = g[t]; xz = g[256 + t]; xn = g[512 + t]; }

        float ar = 0.f, az = 0.f, an = 0.f;
        const half4_t* hp = (const half4_t*)hbuf;
#pragma unroll
        for (int jj = 0; jj < 32; ++jj) {
            half4_t hv = hp[q * 32 + jj];
            half2_t h01 = {hv[0], hv[1]};
            half2_t h23 = {hv[2], hv[3]};
            ar = fdot2(wr[jj * 6 + 0], h01, ar); ar = fdot2(wr[jj * 6 + 1], h23, ar);
            az = fdot2(wr[jj * 6 + 2], h01, az); az = fdot2(wr[jj * 6 + 3], h23, az);
            an = fdot2(wr[jj * 6 + 4], h01, an); an = fdot2(wr[jj * 6 + 5], h23, an);
        }
        part[q * 768 + t]       = ar;
        part[q * 768 + 256 + t] = az;
        part[q * 768 + 512 + t] = an;
        __syncthreads();

        if (q == 0) {
            float hr = part[t]       + part[768 + t];
            float hz = part[256 + t] + part[768 + 256 + t];
            float hn = part[512 + t] + part[768 + 512 + t];
            float r  = 1.f / (1.f + expf(-(xr + br + hr)));
            float z  = 1.f / (1.f + expf(-(xz + bz + hz)));
            float nn = tanhf(xn + r * (hn + bn));
            hprev = (1.f - z) * nn + z * hprev;
            hbuf[t] = (_Float16)hprev;
            hf32[t] = hprev;
        }
        __syncthreads();
    }
    // final step's d write
    if (q == 1) {
        int sl = dir ? 0 : (Sz - 1);
        float hv = hf32[t] * SCL;
        _Float16 hh = (_Float16)hv;
        size_t idx = (size_t)(b * Sz + sl) * 512 + dir * 256 + t;
        dh_out[idx] = hh;
        dl_out[idx] = (_Float16)(hv - (float)hh);
    }
}

// ---------------------------------------------------------------------------
// transpose d (hi,lo) [B*S][512] -> dT (hi,lo) [B][512][256]
__global__ __launch_bounds__(256) void dtrans_kernel(
    const _Float16* __restrict__ dh, const _Float16* __restrict__ dl,
    _Float16* __restrict__ dTh, _Float16* __restrict__ dTl)
{
    __shared__ _Float16 th[64][68];
    __shared__ _Float16 tl[64][68];
    int s0 = blockIdx.x << 6;
    int h0 = blockIdx.y << 6;
    int b  = blockIdx.z;
    int tid = threadIdx.x;
#pragma unroll
    for (int i = 0; i < 16; ++i) {
        int idx = tid + i * 256;
        int s = idx >> 6, h = idx & 63;
        size_t gi = (size_t)(b * 256 + s0 + s) * 512 + h0 + h;
        th[s][h] = dh[gi];
        tl[s][h] = dl[gi];
    }
    __syncthreads();
#pragma unroll
    for (int i = 0; i < 16; ++i) {
        int idx = tid + i * 256;
        int h = idx >> 6, s = idx & 63;
        size_t gi = (size_t)(b * 512 + h0 + h) * 256 + s0 + s;
        dTh[gi] = th[s][h];
        dTl[gi] = tl[s][h];
    }
}

// ---------------------------------------------------------------------------
// BN stats over (b, e) for each channel c (layout y[b][CH][256]), f32 input
__global__ void bn_stats_kernel(const float* __restrict__ y, int CH,
                                float* __restrict__ mean, float* __restrict__ istd)
{
    int c = blockIdx.x, t = threadIdx.x;
    float s = 0.f, ss = 0.f;
    for (int b = 0; b < Bz; ++b) {
        float v = y[((long)b * CH + c) * 256 + t];
        s += v; ss += v * v;
    }
    __shared__ float rs[256], rss[256];
    rs[t] = s; rss[t] = ss; __syncthreads();
    for (int off = 128; off > 0; off >>= 1) {
        if (t < off) { rs[t] += rs[t + off]; rss[t] += rss[t + off]; }
        __syncthreads();
    }
    if (t == 0) {
        float cnt = (float)(Bz * 256);
        float m = rs[0] / cnt;
        float var = rss[0] / cnt - m * m;
        mean[c] = m;
        istd[c] = rsqrtf(var + 1e-5f);
    }
}

// BN stats, f16 (SCL-scaled) input — scale cancels in apply (mean' = SCL*mean,
// istd' = istd/SCL, (y'-mean')*istd' == (y-mean)*istd).
__global__ void bn_stats16_kernel(const _Float16* __restrict__ y, int CH,
                                  float* __restrict__ mean, float* __restrict__ istd)
{
    int c = blockIdx.x, t = threadIdx.x;
    float s = 0.f, ss = 0.f;
    for (int b = 0; b < Bz; ++b) {
        float v = (float)y[((long)b * CH + c) * 256 + t];
        s += v; ss += v * v;
    }
    __shared__ float rs[256], rss[256];
    rs[t] = s; rss[t] = ss; __syncthreads();
    for (int off = 128; off > 0; off >>= 1) {
        if (t < off) { rs[t] += rs[t + off]; rss[t] += rss[t + off]; }
        __syncthreads();
    }
    if (t == 0) {
        float cnt = (float)(Bz * 256);
        float m = rs[0] / cnt;
        float var = rss[0] / cnt - m * m;
        mean[c] = m;
        istd[c] = rsqrtf(var + 1e-5f);
    }
}

// BN1 apply + relu -> scaled hi/lo f16
__global__ void bn_apply_relu_kernel(const float* __restrict__ y,
                                     _Float16* __restrict__ yh, _Float16* __restrict__ yl,
                                     const float* __restrict__ mean, const float* __restrict__ istd,
                                     const float* __restrict__ g, const float* __restrict__ be)
{
    long i = (long)blockIdx.x * 256 + threadIdx.x;
    int c = (int)((i >> 8) % Sz);
    float v = (y[i] - mean[c]) * istd[c] * g[c] + be[c];
    v = fmaxf(v, 0.f);
    float t = v * SCL;
    _Float16 h = (_Float16)t;
    yh[i] = h;
    yl[i] = (_Float16)(t - (float)h);
}

// ---------------------------------------------------------------------------
// Fused BN2-apply + tanh + cosine-similarity output; epre is SCL-scaled f16
// (scale cancels: mean/istd computed on the same scaled values).
__global__ void bn_tanh_out_kernel(const _Float16* __restrict__ epre16,
                                   const float* __restrict__ mean, const float* __restrict__ istd,
                                   const float* __restrict__ g, const float* __restrict__ be,
                                   const float* __restrict__ Vsum, const float* __restrict__ vnorm,
                                   float* __restrict__ out)
{
    int bl = blockIdx.x;               // b*Lz + l
    int l = bl & (Lz - 1);
    int t = threadIdx.x;
    float v = ((float)epre16[(long)bl * 256 + t] - mean[l]) * istd[l] * g[l] + be[l];
    float ev = tanhf(v);
    float vv = Vsum[l * 256 + t];
    __shared__ float rd[256], rn[256];
    rd[t] = ev * vv; rn[t] = ev * ev; __syncthreads();
    for (int off = 128; off > 0; off >>= 1) {
        if (t < off) { rd[t] += rd[t + off]; rn[t] += rn[t + off]; }
        __syncthreads();
    }
    if (t == 0) {
        float num = rd[0];
        float den = fmaxf(sqrtf(rn[0]), 1e-8f) * fmaxf(vnorm[l], 1e-8f);
        out[bl] = num / den * 10.f;
    }
}

// ---------------------------------------------------------------------------
extern "C" void kernel_launch(void* const* d_in, const int* in_sizes, int n_in,
                              void* d_out, int out_size, void* d_ws, size_t ws_size,
                              hipStream_t stream)
{
    const int*   x      = (const int*)d_in[0];
    const int*   V_idx  = (const int*)d_in[1];
    const float* emb    = (const float*)d_in[2];
    const float* w_ih_f = (const float*)d_in[3];
    const float* w_hh_f = (const float*)d_in[4];
    const float* b_ih_f = (const float*)d_in[5];
    const float* b_hh_f = (const float*)d_in[6];
    const float* w_ih_b = (const float*)d_in[7];
    const float* w_hh_b = (const float*)d_in[8];
    const float* b_ih_b = (const float*)d_in[9];
    const float* b_hh_b = (const float*)d_in[10];
    const float* w1     = (const float*)d_in[11];
    const float* b1     = (const float*)d_in[12];
    const float* w2     = (const float*)d_in[13];
    const float* b2     = (const float*)d_in[14];
    const float* g1     = (const float*)d_in[15];
    const float* be1    = (const float*)d_in[16];
    const float* g2     = (const float*)d_in[17];
    const float* be2    = (const float*)d_in[18];

    float* ws = (float*)d_ws;
    float* out = (float*)d_out;

    // ---- workspace layout (float units); total ~207 MB (round-4 proven) ----
    float*    vsum   = ws;                               // 262144
    float*    vnorm  = ws + 262144;                      // 1024
    float*    mean   = ws + 263168;                      // 1024
    float*    istd   = ws + 264192;                      // 1024
    half2_t*  wqf    = (half2_t*)(ws + 265216);          // 98304
    half2_t*  wqb    = (half2_t*)(ws + 363520);          // 98304
    _Float16* vsh    = (_Float16*)(ws + 461824);         // 131072 fl
    _Float16* vsl    = (_Float16*)(ws + 592896);         // 131072 fl
    _Float16* wihh_f = (_Float16*)(ws + 723968);         // 98304 fl
    _Float16* wihl_f = (_Float16*)(ws + 822272);         // 98304 fl
    _Float16* wihh_b = (_Float16*)(ws + 920576);         // 98304 fl (f->b stride 393216 halves)
    _Float16* wihl_b = (_Float16*)(ws + 1018880);        // 98304 fl
    _Float16* w1h    = (_Float16*)(ws + 1117184);        // 65536 fl
    _Float16* w1l    = (_Float16*)(ws + 1182720);        // 65536 fl
    _Float16* w2h    = (_Float16*)(ws + 1248256);        // 65536 fl
    _Float16* w2l    = (_Float16*)(ws + 1313792);        // 65536 fl (unused this round)
    float*    AB     = ws + 1379328;                     // overlay arena
    _Float16* xeh    = (_Float16*)(AB + 0);              // st1-2
    _Float16* xel    = (_Float16*)(AB + 2097152);
    float*    gxf    = AB + 4194304;                     // st2-3 (f->b stride 12582912 fl)
    float*    gxb    = AB + 16777216;
    _Float16* dh     = (_Float16*)(AB + 29360128);       // st3-4 (+dtrans)
    _Float16* dl     = (_Float16*)(AB + 33554432);
    _Float16* dTh    = (_Float16*)(AB + 0);              // dtrans-st6 (xe/gx dead)
    _Float16* dTl    = (_Float16*)(AB + 4194304);
    float*    d2pre  = AB + 8388608;                     // st4 (gx dead)
    _Float16* d2h    = (_Float16*)(AB + 12582912);       // st4-5
    _Float16* d2l    = (_Float16*)(AB + 14680064);
    _Float16* ah     = (_Float16*)(AB + 16777216);       // st5-6 (gxb/d dead)
    _Float16* c16    = (_Float16*)(AB + 33554432);       // st6-7 (dl dead)
    _Float16* epre16 = (_Float16*)(AB + 0);              // st7-8 (dT/d2 dead) 33MB

    // Stage 1: gathers + packs
    vsum_kernel<<<Lz, 256, 0, stream>>>(V_idx, emb, vsum, vsh, vsl, vnorm);
    xe_kernel<<<Bz * Sz, 256, 0, stream>>>(x, emb, xeh, xel);
    wpack_kernel<<<384, 256, 0, stream>>>(w_hh_f, w_hh_b, wqf, wqb);
    cvtsplit_kernel<<<768, 256, 0, stream>>>(w_ih_f, wihh_f, wihl_f, 196608);
    cvtsplit_kernel<<<768, 256, 0, stream>>>(w_ih_b, wihh_b, wihl_b, 196608);
    cvtsplit_kernel<<<512, 256, 0, stream>>>(w1, w1h, w1l, 131072);
    cvtsplit_kernel<<<512, 256, 0, stream>>>(w2, w2h, w2l, 131072);

    // Stage 2 (merged f+b via grid.z): gx = xe @ w_ih^T + b_ih  (M=16384, N=768, K=256)
    gemm_mfma<0, 1, 0, 1, 1><<<dim3(6, 128, 2), 256, 0, stream>>>(
        xeh, xel, wihh_f, wihl_f, b_ih_f, b_ih_b, gxf, nullptr, nullptr,
        Bz * Sz, 768, Ez, 0, 393216, 12582912);

    // Stage 3: GRU (round-4 exact) -> d hi/lo; transpose -> dT [B,512,256]
    gru_kernel<<<128, 512, 0, stream>>>(gxf, gxb, wqf, wqb, b_hh_f, b_hh_b, dh, dl);
    dtrans_kernel<<<dim3(4, 8, Bz), 256, 0, stream>>>(dh, dl, dTh, dTl);

    // Stage 4: d2pre = d @ w1^T + b1 (M=16384, N=256, K=512) f32; BN1+relu -> hi/lo
    // (d-lo and w1-lo kept: errors here enter the a-chain, r8-calibrated 10-30x)
    gemm_mfma<0, 1, 0, 1, 1><<<dim3(2, 128, 1), 256, 0, stream>>>(
        dh, dl, w1h, w1l, b1, b1, d2pre, nullptr, nullptr, Bz * Sz, Ez, 512, 0, 0, 0);
    bn_stats_kernel<<<Sz, 256, 0, stream>>>(d2pre, Sz, mean, istd);
    bn_apply_relu_kernel<<<Bz * Sz, 256, 0, stream>>>(d2pre, d2h, d2l, mean, istd, g1, be1);

    // Stage 5: a[b] = tanh(Vsum @ d2[b]^T)  (M=1024, N=256, K=256) -> hi only
    gemm_mfma<2, 0, 2, 1, 1><<<dim3(2, 8, Bz), 256, 0, stream>>>(
        vsh, vsl, d2h, d2l, nullptr, nullptr, nullptr, ah, nullptr,
        Lz, Sz, Ez, 0, (long)Sz * Ez, (long)Lz * Sz);

    // Stage 6: c[b] = relu(a[b] @ dT[b]^T)  (M=1024, N=512, K=256), A hi-only
    gemm_mfma<1, 0, 2, 0, 1><<<dim3(4, 8, Bz), 256, 0, stream>>>(
        ah, nullptr, dTh, dTl, nullptr, nullptr, nullptr, c16, nullptr, Lz, 512, Sz,
        (long)Lz * Sz, (long)512 * Sz, (long)Lz * 512);

    // Stage 7: epre = c @ w2^T + b2 (M=65536, N=256, K=512) — LAST-LAYER levers:
    // A hi-only + B hi-only (w2-lo dropped) = single MFMA pass; output scaled
    // f16 (OUTM=2). Both errors enter only e_pre (late-stage, ~1-3x to out).
    gemm_mfma<0, 1, 2, 0, 0><<<dim3(2, 512, 1), 256, 0, stream>>>(
        c16, nullptr, w2h, nullptr, b2, b2, nullptr, epre16, nullptr,
        Bz * Lz, Ez, 512, 0, 0, 0);
    bn_stats16_kernel<<<Lz, 256, 0, stream>>>(epre16, Lz, mean, istd);

    // Stage 8: fused BN2-apply + tanh + cosine output (f16 epre)
    bn_tanh_out_kernel<<<Bz * Lz, 256, 0, stream>>>(epre16, mean, istd, g2, be2, vsum, vnorm, out);
}

// Round 14
// 611.616 us; speedup vs baseline: 1.4553x; 1.0599x over previous
//
#include <hip/hip_runtime.h>
#include <hip/hip_bf16.h>

// Sizes (fixed per problem)
#define Bz 64
#define Sz 256
#define Ez 256
#define Hz 256
#define Lz 1024
#define VLz 16

// split-precision scale: x stored as hi+lo of (x*SCL); products carry SCL^2
#define SCL 64.0f
#define DESCL (1.0f / 4096.0f)
#define INV_SCL 0.015625f

typedef _Float16 half2_t __attribute__((ext_vector_type(2)));
typedef _Float16 half4_t __attribute__((ext_vector_type(4)));
typedef _Float16 f16x8   __attribute__((ext_vector_type(8)));
typedef float    f32x4   __attribute__((ext_vector_type(4)));

__device__ inline float fdot2(half2_t a, half2_t b, float c) {
#if __has_builtin(__builtin_amdgcn_fdot2)
    return __builtin_amdgcn_fdot2(a, b, c, false);
#else
    return c + (float)a[0] * (float)b[0] + (float)a[1] * (float)b[1];
#endif
}

// async global->LDS 16B; LDS dest must be linear lane-ordered (m104/m173)
__device__ inline void stage16(_Float16* ldst, const _Float16* gsrc) {
#if __has_builtin(__builtin_amdgcn_global_load_lds)
    __builtin_amdgcn_global_load_lds(
        (const __attribute__((address_space(1))) unsigned int*)gsrc,
        (__attribute__((address_space(3))) unsigned int*)ldst, 16, 0, 0);
#else
    *(f16x8*)ldst = *(const f16x8*)gsrc;
#endif
}

// ---------------------------------------------------------------------------
// K1: Vsum[l,e] = sum_j emb[V_idx[l,j], e]; norms; hi/lo split copy
// (vsum-lo is LOAD-BEARING: r8-vs-r12 isolated its drop to +0.03 absmax)
__global__ void vsum_kernel(const int* __restrict__ V_idx, const float* __restrict__ emb,
                            float* __restrict__ Vsum, _Float16* __restrict__ vsh,
                            _Float16* __restrict__ vsl, float* __restrict__ vnorm)
{
    int l = blockIdx.x, e = threadIdx.x;
    float s = 0.f;
#pragma unroll
    for (int j = 0; j < VLz; ++j) {
        int idx = V_idx[l * VLz + j];
        s += emb[(long)idx * Ez + e];
    }
    Vsum[l * Ez + e] = s;
    float t = s * SCL;
    _Float16 h = (_Float16)t;
    vsh[l * Ez + e] = h;
    vsl[l * Ez + e] = (_Float16)(t - (float)h);
    __shared__ float red[256];
    red[e] = s * s; __syncthreads();
    for (int off = 128; off > 0; off >>= 1) { if (e < off) red[e] += red[e + off]; __syncthreads(); }
    if (e == 0) vnorm[l] = sqrtf(red[0]);
}

// K2: xe gather, hi only (xe-lo dropped this round: its pass in stage 2 was
// removed; gx is stored f16 anyway so xe-lo precision was below the noise)
__global__ void xe_kernel(const int* __restrict__ x, const float* __restrict__ emb,
                          _Float16* __restrict__ xeh)
{
    int i = blockIdx.x;              // b*S+s
    int e = threadIdx.x;
    float v = emb[(long)x[i] * Ez + e] * SCL;
    xeh[(long)i * Ez + e] = (_Float16)v;
}

// K3: pack w_hh [768,256] fp32 -> f16x2 quad layout for the GRU (round-2/4 proven).
__global__ void wpack_kernel(const float* __restrict__ w_f, const float* __restrict__ w_b,
                             half2_t* __restrict__ out_f, half2_t* __restrict__ out_b)
{
    int i = blockIdx.x * 256 + threadIdx.x;   // 0 .. 98303
    int t = i & 255;
    int rest = i >> 8;          // (kq*3+g)*2+p
    int p = rest & 1;
    int gq = rest >> 1;
    int g = gq % 3;
    int kq = gq / 3;
    int o = g * 256 + t;
    int k = 4 * kq + 2 * p;
    out_f[i] = half2_t{(_Float16)w_f[o * 256 + k], (_Float16)w_f[o * 256 + k + 1]};
    out_b[i] = half2_t{(_Float16)w_b[o * 256 + k], (_Float16)w_b[o * 256 + k + 1]};
}

// fused f32 -> scaled hi/lo f16 for all four weight matrices (one launch)
__global__ void cvtsplit4_kernel(
    const float* __restrict__ wihf, const float* __restrict__ wihb,
    const float* __restrict__ w1,   const float* __restrict__ w2,
    _Float16* wihh_f, _Float16* wihl_f, _Float16* wihh_b, _Float16* wihl_b,
    _Float16* w1h, _Float16* w1l, _Float16* w2h, _Float16* w2l)
{
    int i = blockIdx.x * 256 + threadIdx.x;   // 0 .. 655359
    const float* src; _Float16 *dh_, *dl_; int j;
    if (i < 196608)      { src = wihf; dh_ = wihh_f; dl_ = wihl_f; j = i; }
    else if (i < 393216) { src = wihb; dh_ = wihh_b; dl_ = wihl_b; j = i - 196608; }
    else if (i < 524288) { src = w1;   dh_ = w1h;    dl_ = w1l;    j = i - 393216; }
    else                 { src = w2;   dh_ = w2h;    dl_ = w2l;    j = i - 524288; }
    float v = src[j] * SCL;
    _Float16 h = (_Float16)v;
    dh_[j] = h;
    dl_[j] = (_Float16)(v - (float)h);
}

// ---------------------------------------------------------------------------
// Split-precision MFMA NT GEMM: C = (1/4096)*(Ah[+Al])@(Bh[+Bl])^T (+bias)(+epi).
// acc = Ah*Bh (+ Ah*Bl if SPLIT_B) (+ Al*Bh if SPLIT_A). BM=BN=128, BK=32.
// OUTM: 0 = f32 C, 1 = scaled hi/lo f16 (Ch,Cl), 2 = scaled hi f16 only.
// bias_b: alternate bias selected when blockIdx.z==1 (merged f/b dispatches).
template<int EPI, int BIAS, int OUTM, int SPLIT_A, int SPLIT_B>
__global__ __launch_bounds__(256, 2) void gemm_mfma(
    const _Float16* __restrict__ Ah, const _Float16* __restrict__ Al,
    const _Float16* __restrict__ Bh, const _Float16* __restrict__ Bl,
    const float* __restrict__ bias, const float* __restrict__ bias_b,
    float* __restrict__ C, _Float16* __restrict__ Ch, _Float16* __restrict__ Cl,
    int M, int N, int K, long sA, long sB, long sC)
{
    int bz = blockIdx.z;
    Ah += (long)bz * sA;
    if (SPLIT_A) Al += (long)bz * sA;
    Bh += (long)bz * sB;
    if (SPLIT_B) Bl += (long)bz * sB;
    const float* bp = BIAS ? (bz ? bias_b : bias) : nullptr;
    __shared__ __attribute__((aligned(16))) _Float16 Ash[128 * 32];
    __shared__ __attribute__((aligned(16))) _Float16 Asl[128 * 32];
    __shared__ __attribute__((aligned(16))) _Float16 Bsh[128 * 32];
    __shared__ __attribute__((aligned(16))) _Float16 Bsl[128 * 32];
    int tid = threadIdx.x;
    int lane = tid & 63;
    int wid = tid >> 6;
    int wm = wid >> 1, wn = wid & 1;
    int m0 = blockIdx.y * 128, n0 = blockIdx.x * 128;

    int srow = tid >> 2, sslot = tid & 3;
    int sw0 = sslot ^ ((srow >> 1) & 3);
    long a0 = (long)(m0 + srow) * K + sw0 * 8;
    long a1 = (long)(m0 + 64 + srow) * K + sw0 * 8;
    long b0 = (long)(n0 + srow) * K + sw0 * 8;
    long b1 = (long)(n0 + 64 + srow) * K + sw0 * 8;

    f32x4 acc[4][4] = {};
    int r16 = lane & 15, kg = lane >> 4;

    for (int k0 = 0; k0 < K; k0 += 32) {
        stage16(&Ash[tid * 8],        Ah + a0 + k0);
        stage16(&Ash[2048 + tid * 8], Ah + a1 + k0);
        if (SPLIT_A) {
            stage16(&Asl[tid * 8],        Al + a0 + k0);
            stage16(&Asl[2048 + tid * 8], Al + a1 + k0);
        }
        stage16(&Bsh[tid * 8],        Bh + b0 + k0);
        stage16(&Bsh[2048 + tid * 8], Bh + b1 + k0);
        if (SPLIT_B) {
            stage16(&Bsl[tid * 8],        Bl + b0 + k0);
            stage16(&Bsl[2048 + tid * 8], Bl + b1 + k0);
        }
        __syncthreads();
        f16x8 afh[4], afl[4], bfh[4], bfl[4];
#pragma unroll
        for (int mi = 0; mi < 4; ++mi) {
            int r = wm * 64 + mi * 16 + r16;
            int sl = kg ^ ((r >> 1) & 3);
            int off = r * 32 + sl * 8;
            afh[mi] = *(const f16x8*)&Ash[off];
            if (SPLIT_A) afl[mi] = *(const f16x8*)&Asl[off];
        }
#pragma unroll
        for (int ni = 0; ni < 4; ++ni) {
            int n = wn * 64 + ni * 16 + r16;
            int sl = kg ^ ((n >> 1) & 3);
            int off = n * 32 + sl * 8;
            bfh[ni] = *(const f16x8*)&Bsh[off];
            if (SPLIT_B) bfl[ni] = *(const f16x8*)&Bsl[off];
        }
#pragma unroll
        for (int mi = 0; mi < 4; ++mi)
#pragma unroll
            for (int ni = 0; ni < 4; ++ni) {
                acc[mi][ni] = __builtin_amdgcn_mfma_f32_16x16x32_f16(afh[mi], bfh[ni], acc[mi][ni], 0, 0, 0);
                if (SPLIT_B)
                    acc[mi][ni] = __builtin_amdgcn_mfma_f32_16x16x32_f16(afh[mi], bfl[ni], acc[mi][ni], 0, 0, 0);
                if (SPLIT_A)
                    acc[mi][ni] = __builtin_amdgcn_mfma_f32_16x16x32_f16(afl[mi], bfh[ni], acc[mi][ni], 0, 0, 0);
            }
        __syncthreads();
    }

    long coff = (long)bz * sC;
#pragma unroll
    for (int mi = 0; mi < 4; ++mi) {
#pragma unroll
        for (int ni = 0; ni < 4; ++ni) {
            int n = n0 + wn * 64 + ni * 16 + r16;
            float bv = BIAS ? bp[n] : 0.f;
#pragma unroll
            for (int j = 0; j < 4; ++j) {
                int m = m0 + wm * 64 + mi * 16 + kg * 4 + j;
                float v = acc[mi][ni][j] * DESCL + bv;
                if (EPI == 1) v = fmaxf(v, 0.f);
                if (EPI == 2) v = tanhf(v);
                long idx = coff + (long)m * N + n;
                if (OUTM == 0) {
                    C[idx] = v;
                } else if (OUTM == 1) {
                    float t = v * SCL;
                    _Float16 h = (_Float16)t;
                    Ch[idx] = h;
                    Cl[idx] = (_Float16)(t - (float)h);
                } else {
                    Ch[idx] = (_Float16)(v * SCL);
                }
            }
        }
    }
}

// ---------------------------------------------------------------------------
// K4: GRU recurrence — round-4/10 structure (361us, AT the 35.7 TB/s aggregate
// L2 ceiling; r5/r6/r7/r9/r11 variants all measured worse). This round: gx is
// SCL-scaled f16 (halves stage-2 write + GRU gx read; descale on load).
__global__ __launch_bounds__(512, 2) void gru_kernel(
    const _Float16* __restrict__ gx_f, const _Float16* __restrict__ gx_b,
    const half2_t* __restrict__ wq_f, const half2_t* __restrict__ wq_b,
    const float* __restrict__ bhh_f, const float* __restrict__ bhh_b,
    _Float16* __restrict__ dh_out, _Float16* __restrict__ dl_out)
{
    int dir = blockIdx.x >> 6;
    int b   = blockIdx.x & 63;
    const _Float16* gx  = dir ? gx_b : gx_f;
    const half2_t*  wq  = dir ? wq_b : wq_f;
    const float*    bhh = dir ? bhh_b : bhh_f;
    int tid = threadIdx.x;
    int t = tid & 255, q = tid >> 8;

    __shared__ __attribute__((aligned(16))) _Float16 hbuf[256];
    __shared__ float hf32[256];
    __shared__ float part[2 * 768];

    half2_t wr[192];
    const half2_t* wbase = wq + (size_t)q * 192 * 256 + t;
#pragma unroll
    for (int m = 0; m < 192; ++m) wr[m] = wbase[m << 8];

    float br = 0.f, bz = 0.f, bn = 0.f, hprev = 0.f;
    if (q == 0) {
        br = bhh[t]; bz = bhh[256 + t]; bn = bhh[512 + t];
        hbuf[t] = (_Float16)0.f;
        hf32[t] = 0.f;
    }
    __syncthreads();

    for (int step = 0; step < Sz; ++step) {
        int s = dir ? (Sz - 1 - step) : step;
        // deferred previous-step d write (overlaps dot phase)
        if (q == 1 && step > 0) {
            int sp = dir ? (Sz - step) : (step - 1);
            float hv = hf32[t] * SCL;
            _Float16 hh = (_Float16)hv;
            size_t idx = (size_t)(b * Sz + sp) * 512 + dir * 256 + t;
            dh_out[idx] = hh;
            dl_out[idx] = (_Float16)(hv - (float)hh);
        }
        const _Float16* g = gx + (size_t)(b * Sz + s) * 768;
        float xr = 0.f, xz = 0.f, xn = 0.f;
        if (q == 0) {
            xr = (float)g[t] * INV_SCL;
            xz = (float)g[256 + t] * INV_SCL;
            xn = (float)g[512 + t] * INV_SCL;
        }

        float ar = 0.f, az = 0.f, an = 0.f;
        const half4_t* hp = (const half4_t*)hbuf;
#pragma unroll
        for (int jj = 0; jj < 32; ++jj) {
            half4_t hv = hp[q * 32 + jj];
            half2_t h01 = {hv[0], hv[1]};
            half2_t h23 = {hv[2], hv[3]};
            ar = fdot2(wr[jj * 6 + 0], h01, ar); ar = fdot2(wr[jj * 6 + 1], h23, ar);
            az = fdot2(wr[jj * 6 + 2], h01, az); az = fdot2(wr[jj * 6 + 3], h23, az);
            an = fdot2(wr[jj * 6 + 4], h01, an); an = fdot2(wr[jj * 6 + 5], h23, an);
        }
        part[q * 768 + t]       = ar;
        part[q * 768 + 256 + t] = az;
        part[q * 768 + 512 + t] = an;
        __syncthreads();

        if (q == 0) {
            float hr = part[t]       + part[768 + t];
            float hz = part[256 + t] + part[768 + 256 + t];
            float hn = part[512 + t] + part[768 + 512 + t];
            float r  = 1.f / (1.f + expf(-(xr + br + hr)));
            float z  = 1.f / (1.f + expf(-(xz + bz + hz)));
            float nn = tanhf(xn + r * (hn + bn));
            hprev = (1.f - z) * nn + z * hprev;
            hbuf[t] = (_Float16)hprev;
            hf32[t] = hprev;
        }
        __syncthreads();
    }
    // final step's d write
    if (q == 1) {
        int sl = dir ? 0 : (Sz - 1);
        float hv = hf32[t] * SCL;
        _Float16 hh = (_Float16)hv;
        size_t idx = (size_t)(b * Sz + sl) * 512 + dir * 256 + t;
        dh_out[idx] = hh;
        dl_out[idx] = (_Float16)(hv - (float)hh);
    }
}

// ---------------------------------------------------------------------------
// transpose d (hi,lo) [B*S][512] -> dT (hi,lo) [B][512][256]
__global__ __launch_bounds__(256) void dtrans_kernel(
    const _Float16* __restrict__ dh, const _Float16* __restrict__ dl,
    _Float16* __restrict__ dTh, _Float16* __restrict__ dTl)
{
    __shared__ _Float16 th[64][68];
    __shared__ _Float16 tl[64][68];
    int s0 = blockIdx.x << 6;
    int h0 = blockIdx.y << 6;
    int b  = blockIdx.z;
    int tid = threadIdx.x;
#pragma unroll
    for (int i = 0; i < 16; ++i) {
        int idx = tid + i * 256;
        int s = idx >> 6, h = idx & 63;
        size_t gi = (size_t)(b * 256 + s0 + s) * 512 + h0 + h;
        th[s][h] = dh[gi];
        tl[s][h] = dl[gi];
    }
    __syncthreads();
#pragma unroll
    for (int i = 0; i < 16; ++i) {
        int idx = tid + i * 256;
        int h = idx >> 6, s = idx & 63;
        size_t gi = (size_t)(b * 512 + h0 + h) * 256 + s0 + s;
        dTh[gi] = th[s][h];
        dTl[gi] = tl[s][h];
    }
}

// ---------------------------------------------------------------------------
// BN stats over (b, e) for each channel c (layout y[b][CH][256]), f32 input
__global__ void bn_stats_kernel(const float* __restrict__ y, int CH,
                                float* __restrict__ mean, float* __restrict__ istd)
{
    int c = blockIdx.x, t = threadIdx.x;
    float s = 0.f, ss = 0.f;
    for (int b = 0; b < Bz; ++b) {
        float v = y[((long)b * CH + c) * 256 + t];
        s += v; ss += v * v;
    }
    __shared__ float rs[256], rss[256];
    rs[t] = s; rss[t] = ss; __syncthreads();
    for (int off = 128; off > 0; off >>= 1) {
        if (t < off) { rs[t] += rs[t + off]; rss[t] += rss[t + off]; }
        __syncthreads();
    }
    if (t == 0) {
        float cnt = (float)(Bz * 256);
        float m = rs[0] / cnt;
        float var = rss[0] / cnt - m * m;
        mean[c] = m;
        istd[c] = rsqrtf(var + 1e-5f);
    }
}

// BN stats, f16 (SCL-scaled) input — scale cancels in apply.
__global__ void bn_stats16_kernel(const _Float16* __restrict__ y, int CH,
                                  float* __restrict__ mean, float* __restrict__ istd)
{
    int c = blockIdx.x, t = threadIdx.x;
    float s = 0.f, ss = 0.f;
    for (int b = 0; b < Bz; ++b) {
        float v = (float)y[((long)b * CH + c) * 256 + t];
        s += v; ss += v * v;
    }
    __shared__ float rs[256], rss[256];
    rs[t] = s; rss[t] = ss; __syncthreads();
    for (int off = 128; off > 0; off >>= 1) {
        if (t < off) { rs[t] += rs[t + off]; rss[t] += rss[t + off]; }
        __syncthreads();
    }
    if (t == 0) {
        float cnt = (float)(Bz * 256);
        float m = rs[0] / cnt;
        float var = rss[0] / cnt - m * m;
        mean[c] = m;
        istd[c] = rsqrtf(var + 1e-5f);
    }
}

// BN1 apply + relu -> scaled hi/lo f16
__global__ void bn_apply_relu_kernel(const float* __restrict__ y,
                                     _Float16* __restrict__ yh, _Float16* __restrict__ yl,
                                     const float* __restrict__ mean, const float* __restrict__ istd,
                                     const float* __restrict__ g, const float* __restrict__ be)
{
    long i = (long)blockIdx.x * 256 + threadIdx.x;
    int c = (int)((i >> 8) % Sz);
    float v = (y[i] - mean[c]) * istd[c] * g[c] + be[c];
    v = fmaxf(v, 0.f);
    float t = v * SCL;
    _Float16 h = (_Float16)t;
    yh[i] = h;
    yl[i] = (_Float16)(t - (float)h);
}

// ---------------------------------------------------------------------------
// Fused BN2-apply + tanh + cosine-similarity output; epre is SCL-scaled f16
__global__ void bn_tanh_out_kernel(const _Float16* __restrict__ epre16,
                                   const float* __restrict__ mean, const float* __restrict__ istd,
                                   const float* __restrict__ g, const float* __restrict__ be,
                                   const float* __restrict__ Vsum, const float* __restrict__ vnorm,
                                   float* __restrict__ out)
{
    int bl = blockIdx.x;               // b*Lz + l
    int l = bl & (Lz - 1);
    int t = threadIdx.x;
    float v = ((float)epre16[(long)bl * 256 + t] - mean[l]) * istd[l] * g[l] + be[l];
    float ev = tanhf(v);
    float vv = Vsum[l * 256 + t];
    __shared__ float rd[256], rn[256];
    rd[t] = ev * vv; rn[t] = ev * ev; __syncthreads();
    for (int off = 128; off > 0; off >>= 1) {
        if (t < off) { rd[t] += rd[t + off]; rn[t] += rn[t + off]; }
        __syncthreads();
    }
    if (t == 0) {
        float num = rd[0];
        float den = fmaxf(sqrtf(rn[0]), 1e-8f) * fmaxf(vnorm[l], 1e-8f);
        out[bl] = num / den * 10.f;
    }
}

// ---------------------------------------------------------------------------
extern "C" void kernel_launch(void* const* d_in, const int* in_sizes, int n_in,
                              void* d_out, int out_size, void* d_ws, size_t ws_size,
                              hipStream_t stream)
{
    const int*   x      = (const int*)d_in[0];
    const int*   V_idx  = (const int*)d_in[1];
    const float* emb    = (const float*)d_in[2];
    const float* w_ih_f = (const float*)d_in[3];
    const float* w_hh_f = (const float*)d_in[4];
    const float* b_ih_f = (const float*)d_in[5];
    const float* b_hh_f = (const float*)d_in[6];
    const float* w_ih_b = (const float*)d_in[7];
    const float* w_hh_b = (const float*)d_in[8];
    const float* b_ih_b = (const float*)d_in[9];
    const float* b_hh_b = (const float*)d_in[10];
    const float* w1     = (const float*)d_in[11];
    const float* b1     = (const float*)d_in[12];
    const float* w2     = (const float*)d_in[13];
    const float* b2     = (const float*)d_in[14];
    const float* g1     = (const float*)d_in[15];
    const float* be1    = (const float*)d_in[16];
    const float* g2     = (const float*)d_in[17];
    const float* be2    = (const float*)d_in[18];

    float* ws = (float*)d_ws;
    float* out = (float*)d_out;

    // ---- workspace layout (float units) ----
    float*    vsum   = ws;                               // 262144
    float*    vnorm  = ws + 262144;                      // 1024
    float*    mean   = ws + 263168;                      // 1024
    float*    istd   = ws + 264192;                      // 1024
    half2_t*  wqf    = (half2_t*)(ws + 265216);          // 98304
    half2_t*  wqb    = (half2_t*)(ws + 363520);          // 98304
    _Float16* vsh    = (_Float16*)(ws + 461824);         // 131072 fl
    _Float16* vsl    = (_Float16*)(ws + 592896);         // 131072 fl
    _Float16* wihh_f = (_Float16*)(ws + 723968);         // 98304 fl
    _Float16* wihl_f = (_Float16*)(ws + 822272);         // 98304 fl
    _Float16* wihh_b = (_Float16*)(ws + 920576);         // 98304 fl (f->b stride 393216 halves)
    _Float16* wihl_b = (_Float16*)(ws + 1018880);        // 98304 fl
    _Float16* w1h    = (_Float16*)(ws + 1117184);        // 65536 fl
    _Float16* w1l    = (_Float16*)(ws + 1182720);        // 65536 fl
    _Float16* w2h    = (_Float16*)(ws + 1248256);        // 65536 fl
    _Float16* w2l    = (_Float16*)(ws + 1313792);        // 65536 fl (unused by GEMMs)
    float*    AB     = ws + 1379328;                     // overlay arena
    _Float16* xeh    = (_Float16*)(AB + 0);              // st1-2 (4.19M fl16)
    _Float16* gx16f  = (_Float16*)(AB + 4194304);        // st2-3: 12.58M halves
    _Float16* gx16b  = (_Float16*)(AB + 10485760);       //        (f->b stride 12582912 halves)
    _Float16* dh     = (_Float16*)(AB + 29360128);       // st3-4 (+dtrans)
    _Float16* dl     = (_Float16*)(AB + 33554432);
    _Float16* dTh    = (_Float16*)(AB + 0);              // dtrans-st6 (xe/gx dead)
    _Float16* dTl    = (_Float16*)(AB + 4194304);
    float*    d2pre  = AB + 8388608;                     // st4 (gx dead)
    _Float16* d2h    = (_Float16*)(AB + 12582912);       // st4-5
    _Float16* d2l    = (_Float16*)(AB + 14680064);
    _Float16* ah     = (_Float16*)(AB + 16777216);       // st5-6 (gx/d dead)
    _Float16* c16    = (_Float16*)(AB + 33554432);       // st6-7 (dl dead)
    _Float16* epre16 = (_Float16*)(AB + 0);              // st7-8 (dT/d2 dead) 33MB

    // Stage 1: gathers + packs (cvtsplit x4 fused into one launch)
    vsum_kernel<<<Lz, 256, 0, stream>>>(V_idx, emb, vsum, vsh, vsl, vnorm);
    xe_kernel<<<Bz * Sz, 256, 0, stream>>>(x, emb, xeh);
    wpack_kernel<<<384, 256, 0, stream>>>(w_hh_f, w_hh_b, wqf, wqb);
    cvtsplit4_kernel<<<2560, 256, 0, stream>>>(
        w_ih_f, w_ih_b, w1, w2,
        wihh_f, wihl_f, wihh_b, wihl_b, w1h, w1l, w2h, w2l);

    // Stage 2 (merged f+b): gx = xe @ w_ih^T + b_ih (M=16384, N=768, K=256)
    // This round's numeric lever: A hi-only (2 passes) + scaled-f16 output.
    // gx errors enter gates fresh each step (non-compounding, unlike h).
    gemm_mfma<0, 1, 2, 0, 1><<<dim3(6, 128, 2), 256, 0, stream>>>(
        xeh, nullptr, wihh_f, wihl_f, b_ih_f, b_ih_b, nullptr, gx16f, nullptr,
        Bz * Sz, 768, Ez, 0, 393216, 12582912);

    // Stage 3: GRU (f16 gx) -> d hi/lo; transpose -> dT [B,512,256]
    gru_kernel<<<128, 512, 0, stream>>>(gx16f, gx16b, wqf, wqb, b_hh_f, b_hh_b, dh, dl);
    dtrans_kernel<<<dim3(4, 8, Bz), 256, 0, stream>>>(dh, dl, dTh, dTl);

    // Stage 4: d2pre = d @ w1^T + b1 (M=16384, N=256, K=512) f32; BN1+relu -> hi/lo
    // (d-lo and w1-lo kept: errors here enter the a-chain, r8-calibrated ~10-30x)
    gemm_mfma<0, 1, 0, 1, 1><<<dim3(2, 128, 1), 256, 0, stream>>>(
        dh, dl, w1h, w1l, b1, b1, d2pre, nullptr, nullptr, Bz * Sz, Ez, 512, 0, 0, 0);
    bn_stats_kernel<<<Sz, 256, 0, stream>>>(d2pre, Sz, mean, istd);
    bn_apply_relu_kernel<<<Bz * Sz, 256, 0, stream>>>(d2pre, d2h, d2l, mean, istd, g1, be1);

    // Stage 5: a[b] = tanh(Vsum @ d2[b]^T)  (M=1024, N=256, K=256) -> hi only
    gemm_mfma<2, 0, 2, 1, 1><<<dim3(2, 8, Bz), 256, 0, stream>>>(
        vsh, vsl, d2h, d2l, nullptr, nullptr, nullptr, ah, nullptr,
        Lz, Sz, Ez, 0, (long)Sz * Ez, (long)Lz * Sz);

    // Stage 6: c[b] = relu(a[b] @ dT[b]^T)  (M=1024, N=512, K=256), A hi-only
    gemm_mfma<1, 0, 2, 0, 1><<<dim3(4, 8, Bz), 256, 0, stream>>>(
        ah, nullptr, dTh, dTl, nullptr, nullptr, nullptr, c16, nullptr, Lz, 512, Sz,
        (long)Lz * Sz, (long)512 * Sz, (long)Lz * 512);

    // Stage 7: epre = c @ w2^T + b2 (M=65536, N=256, K=512) — last-layer:
    // single pass (A,B hi-only), scaled-f16 output (r13-verified free).
    gemm_mfma<0, 1, 2, 0, 0><<<dim3(2, 512, 1), 256, 0, stream>>>(
        c16, nullptr, w2h, nullptr, b2, b2, nullptr, epre16, nullptr,
        Bz * Lz, Ez, 512, 0, 0, 0);
    bn_stats16_kernel<<<Lz, 256, 0, stream>>>(epre16, Lz, mean, istd);

    // Stage 8: fused BN2-apply + tanh + cosine output (f16 epre)
    bn_tanh_out_kernel<<<Bz * Lz, 256, 0, stream>>>(epre16, mean, istd, g2, be2, vsum, vnorm, out);
}

// Round 15
// 588.430 us; speedup vs baseline: 1.5127x; 1.0394x over previous
//
#include <hip/hip_runtime.h>
#include <hip/hip_bf16.h>

// Sizes (fixed per problem)
#define Bz 64
#define Sz 256
#define Ez 256
#define Hz 256
#define Lz 1024
#define VLz 16

// split-precision scale: x stored as hi+lo of (x*SCL); products carry SCL^2
#define SCL 64.0f
#define DESCL (1.0f / 4096.0f)
#define INV_SCL 0.015625f

typedef _Float16 half2_t __attribute__((ext_vector_type(2)));
typedef _Float16 half4_t __attribute__((ext_vector_type(4)));
typedef _Float16 f16x8   __attribute__((ext_vector_type(8)));
typedef float    f32x4   __attribute__((ext_vector_type(4)));

__device__ inline float fdot2(half2_t a, half2_t b, float c) {
#if __has_builtin(__builtin_amdgcn_fdot2)
    return __builtin_amdgcn_fdot2(a, b, c, false);
#else
    return c + (float)a[0] * (float)b[0] + (float)a[1] * (float)b[1];
#endif
}

// async global->LDS 16B; LDS dest must be linear lane-ordered (m104/m173)
__device__ inline void stage16(_Float16* ldst, const _Float16* gsrc) {
#if __has_builtin(__builtin_amdgcn_global_load_lds)
    __builtin_amdgcn_global_load_lds(
        (const __attribute__((address_space(1))) unsigned int*)gsrc,
        (__attribute__((address_space(3))) unsigned int*)ldst, 16, 0, 0);
#else
    *(f16x8*)ldst = *(const f16x8*)gsrc;
#endif
}

// ---------------------------------------------------------------------------
// K1: Vsum[l,e] = sum_j emb[V_idx[l,j], e]; norms; hi/lo split copy
// (vsum-lo is LOAD-BEARING: r8-vs-r12 isolated its drop to +0.03 absmax)
__global__ void vsum_kernel(const int* __restrict__ V_idx, const float* __restrict__ emb,
                            float* __restrict__ Vsum, _Float16* __restrict__ vsh,
                            _Float16* __restrict__ vsl, float* __restrict__ vnorm)
{
    int l = blockIdx.x, e = threadIdx.x;
    float s = 0.f;
#pragma unroll
    for (int j = 0; j < VLz; ++j) {
        int idx = V_idx[l * VLz + j];
        s += emb[(long)idx * Ez + e];
    }
    Vsum[l * Ez + e] = s;
    float t = s * SCL;
    _Float16 h = (_Float16)t;
    vsh[l * Ez + e] = h;
    vsl[l * Ez + e] = (_Float16)(t - (float)h);
    __shared__ float red[256];
    red[e] = s * s; __syncthreads();
    for (int off = 128; off > 0; off >>= 1) { if (e < off) red[e] += red[e + off]; __syncthreads(); }
    if (e == 0) vnorm[l] = sqrtf(red[0]);
}

// K2: xe gather, hi only
__global__ void xe_kernel(const int* __restrict__ x, const float* __restrict__ emb,
                          _Float16* __restrict__ xeh)
{
    int i = blockIdx.x;              // b*S+s
    int e = threadIdx.x;
    float v = emb[(long)x[i] * Ez + e] * SCL;
    xeh[(long)i * Ez + e] = (_Float16)v;
}

// K3: pack w_hh [768,256] fp32 -> f16x2 quad layout for the GRU (round-2/4 proven).
__global__ void wpack_kernel(const float* __restrict__ w_f, const float* __restrict__ w_b,
                             half2_t* __restrict__ out_f, half2_t* __restrict__ out_b)
{
    int i = blockIdx.x * 256 + threadIdx.x;   // 0 .. 98303
    int t = i & 255;
    int rest = i >> 8;          // (kq*3+g)*2+p
    int p = rest & 1;
    int gq = rest >> 1;
    int g = gq % 3;
    int kq = gq / 3;
    int o = g * 256 + t;
    int k = 4 * kq + 2 * p;
    out_f[i] = half2_t{(_Float16)w_f[o * 256 + k], (_Float16)w_f[o * 256 + k + 1]};
    out_b[i] = half2_t{(_Float16)w_b[o * 256 + k], (_Float16)w_b[o * 256 + k + 1]};
}

// fused f32 -> scaled hi/lo f16 for all four weight matrices (one launch)
__global__ void cvtsplit4_kernel(
    const float* __restrict__ wihf, const float* __restrict__ wihb,
    const float* __restrict__ w1,   const float* __restrict__ w2,
    _Float16* wihh_f, _Float16* wihl_f, _Float16* wihh_b, _Float16* wihl_b,
    _Float16* w1h, _Float16* w1l, _Float16* w2h, _Float16* w2l)
{
    int i = blockIdx.x * 256 + threadIdx.x;   // 0 .. 655359
    const float* src; _Float16 *dh_, *dl_; int j;
    if (i < 196608)      { src = wihf; dh_ = wihh_f; dl_ = wihl_f; j = i; }
    else if (i < 393216) { src = wihb; dh_ = wihh_b; dl_ = wihl_b; j = i - 196608; }
    else if (i < 524288) { src = w1;   dh_ = w1h;    dl_ = w1l;    j = i - 393216; }
    else                 { src = w2;   dh_ = w2h;    dl_ = w2l;    j = i - 524288; }
    float v = src[j] * SCL;
    _Float16 h = (_Float16)v;
    dh_[j] = h;
    dl_[j] = (_Float16)(v - (float)h);
}

// ---------------------------------------------------------------------------
// Split-precision MFMA NT GEMM: C = (1/4096)*(Ah[+Al])@(Bh[+Bl])^T (+bias)(+epi).
// acc = Ah*Bh (+ Ah*Bl if SPLIT_B) (+ Al*Bh if SPLIT_A). BM=BN=128, BK=32.
// OUTM: 0 = f32 C, 1 = scaled hi/lo f16 (Ch,Cl), 2 = scaled hi f16 only.
// bias_b: alternate bias selected when blockIdx.z==1 (merged f/b dispatches).
template<int EPI, int BIAS, int OUTM, int SPLIT_A, int SPLIT_B>
__global__ __launch_bounds__(256, 2) void gemm_mfma(
    const _Float16* __restrict__ Ah, const _Float16* __restrict__ Al,
    const _Float16* __restrict__ Bh, const _Float16* __restrict__ Bl,
    const float* __restrict__ bias, const float* __restrict__ bias_b,
    float* __restrict__ C, _Float16* __restrict__ Ch, _Float16* __restrict__ Cl,
    int M, int N, int K, long sA, long sB, long sC)
{
    int bz = blockIdx.z;
    Ah += (long)bz * sA;
    if (SPLIT_A) Al += (long)bz * sA;
    Bh += (long)bz * sB;
    if (SPLIT_B) Bl += (long)bz * sB;
    const float* bp = BIAS ? (bz ? bias_b : bias) : nullptr;
    __shared__ __attribute__((aligned(16))) _Float16 Ash[128 * 32];
    __shared__ __attribute__((aligned(16))) _Float16 Asl[128 * 32];
    __shared__ __attribute__((aligned(16))) _Float16 Bsh[128 * 32];
    __shared__ __attribute__((aligned(16))) _Float16 Bsl[128 * 32];
    int tid = threadIdx.x;
    int lane = tid & 63;
    int wid = tid >> 6;
    int wm = wid >> 1, wn = wid & 1;
    int m0 = blockIdx.y * 128, n0 = blockIdx.x * 128;

    int srow = tid >> 2, sslot = tid & 3;
    int sw0 = sslot ^ ((srow >> 1) & 3);
    long a0 = (long)(m0 + srow) * K + sw0 * 8;
    long a1 = (long)(m0 + 64 + srow) * K + sw0 * 8;
    long b0 = (long)(n0 + srow) * K + sw0 * 8;
    long b1 = (long)(n0 + 64 + srow) * K + sw0 * 8;

    f32x4 acc[4][4] = {};
    int r16 = lane & 15, kg = lane >> 4;

    for (int k0 = 0; k0 < K; k0 += 32) {
        stage16(&Ash[tid * 8],        Ah + a0 + k0);
        stage16(&Ash[2048 + tid * 8], Ah + a1 + k0);
        if (SPLIT_A) {
            stage16(&Asl[tid * 8],        Al + a0 + k0);
            stage16(&Asl[2048 + tid * 8], Al + a1 + k0);
        }
        stage16(&Bsh[tid * 8],        Bh + b0 + k0);
        stage16(&Bsh[2048 + tid * 8], Bh + b1 + k0);
        if (SPLIT_B) {
            stage16(&Bsl[tid * 8],        Bl + b0 + k0);
            stage16(&Bsl[2048 + tid * 8], Bl + b1 + k0);
        }
        __syncthreads();
        f16x8 afh[4], afl[4], bfh[4], bfl[4];
#pragma unroll
        for (int mi = 0; mi < 4; ++mi) {
            int r = wm * 64 + mi * 16 + r16;
            int sl = kg ^ ((r >> 1) & 3);
            int off = r * 32 + sl * 8;
            afh[mi] = *(const f16x8*)&Ash[off];
            if (SPLIT_A) afl[mi] = *(const f16x8*)&Asl[off];
        }
#pragma unroll
        for (int ni = 0; ni < 4; ++ni) {
            int n = wn * 64 + ni * 16 + r16;
            int sl = kg ^ ((n >> 1) & 3);
            int off = n * 32 + sl * 8;
            bfh[ni] = *(const f16x8*)&Bsh[off];
            if (SPLIT_B) bfl[ni] = *(const f16x8*)&Bsl[off];
        }
#pragma unroll
        for (int mi = 0; mi < 4; ++mi)
#pragma unroll
            for (int ni = 0; ni < 4; ++ni) {
                acc[mi][ni] = __builtin_amdgcn_mfma_f32_16x16x32_f16(afh[mi], bfh[ni], acc[mi][ni], 0, 0, 0);
                if (SPLIT_B)
                    acc[mi][ni] = __builtin_amdgcn_mfma_f32_16x16x32_f16(afh[mi], bfl[ni], acc[mi][ni], 0, 0, 0);
                if (SPLIT_A)
                    acc[mi][ni] = __builtin_amdgcn_mfma_f32_16x16x32_f16(afl[mi], bfh[ni], acc[mi][ni], 0, 0, 0);
            }
        __syncthreads();
    }

    long coff = (long)bz * sC;
#pragma unroll
    for (int mi = 0; mi < 4; ++mi) {
#pragma unroll
        for (int ni = 0; ni < 4; ++ni) {
            int n = n0 + wn * 64 + ni * 16 + r16;
            float bv = BIAS ? bp[n] : 0.f;
#pragma unroll
            for (int j = 0; j < 4; ++j) {
                int m = m0 + wm * 64 + mi * 16 + kg * 4 + j;
                float v = acc[mi][ni][j] * DESCL + bv;
                if (EPI == 1) v = fmaxf(v, 0.f);
                if (EPI == 2) v = tanhf(v);
                long idx = coff + (long)m * N + n;
                if (OUTM == 0) {
                    C[idx] = v;
                } else if (OUTM == 1) {
                    float t = v * SCL;
                    _Float16 h = (_Float16)t;
                    Ch[idx] = h;
                    Cl[idx] = (_Float16)(t - (float)h);
                } else {
                    Ch[idx] = (_Float16)(v * SCL);
                }
            }
        }
    }
}

// ---------------------------------------------------------------------------
// K4: GRU recurrence — round-4/10 structure, f16 gx (r14). 350us, streaming
// 12.9GB of weights at the 36.9 TB/s aggregate L2 ceiling. Closed: r5/r6/r7/
// r9/r11 alternatives all measured worse; recurrence caps grid at 128.
__global__ __launch_bounds__(512, 2) void gru_kernel(
    const _Float16* __restrict__ gx_f, const _Float16* __restrict__ gx_b,
    const half2_t* __restrict__ wq_f, const half2_t* __restrict__ wq_b,
    const float* __restrict__ bhh_f, const float* __restrict__ bhh_b,
    _Float16* __restrict__ dh_out, _Float16* __restrict__ dl_out)
{
    int dir = blockIdx.x >> 6;
    int b   = blockIdx.x & 63;
    const _Float16* gx  = dir ? gx_b : gx_f;
    const half2_t*  wq  = dir ? wq_b : wq_f;
    const float*    bhh = dir ? bhh_b : bhh_f;
    int tid = threadIdx.x;
    int t = tid & 255, q = tid >> 8;

    __shared__ __attribute__((aligned(16))) _Float16 hbuf[256];
    __shared__ float hf32[256];
    __shared__ float part[2 * 768];

    half2_t wr[192];
    const half2_t* wbase = wq + (size_t)q * 192 * 256 + t;
#pragma unroll
    for (int m = 0; m < 192; ++m) wr[m] = wbase[m << 8];

    float br = 0.f, bz = 0.f, bn = 0.f, hprev = 0.f;
    if (q == 0) {
        br = bhh[t]; bz = bhh[256 + t]; bn = bhh[512 + t];
        hbuf[t] = (_Float16)0.f;
        hf32[t] = 0.f;
    }
    __syncthreads();

    for (int step = 0; step < Sz; ++step) {
        int s = dir ? (Sz - 1 - step) : step;
        // deferred previous-step d write (overlaps dot phase)
        if (q == 1 && step > 0) {
            int sp = dir ? (Sz - step) : (step - 1);
            float hv = hf32[t] * SCL;
            _Float16 hh = (_Float16)hv;
            size_t idx = (size_t)(b * Sz + sp) * 512 + dir * 256 + t;
            dh_out[idx] = hh;
            dl_out[idx] = (_Float16)(hv - (float)hh);
        }
        const _Float16* g = gx + (size_t)(b * Sz + s) * 768;
        float xr = 0.f, xz = 0.f, xn = 0.f;
        if (q == 0) {
            xr = (float)g[t] * INV_SCL;
            xz = (float)g[256 + t] * INV_SCL;
            xn = (float)g[512 + t] * INV_SCL;
        }

        float ar = 0.f, az = 0.f, an = 0.f;
        const half4_t* hp = (const half4_t*)hbuf;
#pragma unroll
        for (int jj = 0; jj < 32; ++jj) {
            half4_t hv = hp[q * 32 + jj];
            half2_t h01 = {hv[0], hv[1]};
            half2_t h23 = {hv[2], hv[3]};
            ar = fdot2(wr[jj * 6 + 0], h01, ar); ar = fdot2(wr[jj * 6 + 1], h23, ar);
            az = fdot2(wr[jj * 6 + 2], h01, az); az = fdot2(wr[jj * 6 + 3], h23, az);
            an = fdot2(wr[jj * 6 + 4], h01, an); an = fdot2(wr[jj * 6 + 5], h23, an);
        }
        part[q * 768 + t]       = ar;
        part[q * 768 + 256 + t] = az;
        part[q * 768 + 512 + t] = an;
        __syncthreads();

        if (q == 0) {
            float hr = part[t]       + part[768 + t];
            float hz = part[256 + t] + part[768 + 256 + t];
            float hn = part[512 + t] + part[768 + 512 + t];
            float r  = 1.f / (1.f + expf(-(xr + br + hr)));
            float z  = 1.f / (1.f + expf(-(xz + bz + hz)));
            float nn = tanhf(xn + r * (hn + bn));
            hprev = (1.f - z) * nn + z * hprev;
            hbuf[t] = (_Float16)hprev;
            hf32[t] = hprev;
        }
        __syncthreads();
    }
    // final step's d write
    if (q == 1) {
        int sl = dir ? 0 : (Sz - 1);
        float hv = hf32[t] * SCL;
        _Float16 hh = (_Float16)hv;
        size_t idx = (size_t)(b * Sz + sl) * 512 + dir * 256 + t;
        dh_out[idx] = hh;
        dl_out[idx] = (_Float16)(hv - (float)hh);
    }
}

// ---------------------------------------------------------------------------
// transpose d hi [B*S][512] -> dT hi [B][512][256] (dT-lo no longer consumed)
__global__ __launch_bounds__(256) void dtrans_kernel(
    const _Float16* __restrict__ dh, _Float16* __restrict__ dTh)
{
    __shared__ _Float16 th[64][68];
    int s0 = blockIdx.x << 6;
    int h0 = blockIdx.y << 6;
    int b  = blockIdx.z;
    int tid = threadIdx.x;
#pragma unroll
    for (int i = 0; i < 16; ++i) {
        int idx = tid + i * 256;
        int s = idx >> 6, h = idx & 63;
        th[s][h] = dh[(size_t)(b * 256 + s0 + s) * 512 + h0 + h];
    }
    __syncthreads();
#pragma unroll
    for (int i = 0; i < 16; ++i) {
        int idx = tid + i * 256;
        int h = idx >> 6, s = idx & 63;
        dTh[(size_t)(b * 512 + h0 + h) * 256 + s0 + s] = th[s][h];
    }
}

// ---------------------------------------------------------------------------
// BN stats over (b, e) for each channel c (layout y[b][CH][256]), f32 input
__global__ void bn_stats_kernel(const float* __restrict__ y, int CH,
                                float* __restrict__ mean, float* __restrict__ istd)
{
    int c = blockIdx.x, t = threadIdx.x;
    float s = 0.f, ss = 0.f;
    for (int b = 0; b < Bz; ++b) {
        float v = y[((long)b * CH + c) * 256 + t];
        s += v; ss += v * v;
    }
    __shared__ float rs[256], rss[256];
    rs[t] = s; rss[t] = ss; __syncthreads();
    for (int off = 128; off > 0; off >>= 1) {
        if (t < off) { rs[t] += rs[t + off]; rss[t] += rss[t + off]; }
        __syncthreads();
    }
    if (t == 0) {
        float cnt = (float)(Bz * 256);
        float m = rs[0] / cnt;
        float var = rss[0] / cnt - m * m;
        mean[c] = m;
        istd[c] = rsqrtf(var + 1e-5f);
    }
}

// BN stats, f16 (SCL-scaled) input — scale cancels in apply.
__global__ void bn_stats16_kernel(const _Float16* __restrict__ y, int CH,
                                  float* __restrict__ mean, float* __restrict__ istd)
{
    int c = blockIdx.x, t = threadIdx.x;
    float s = 0.f, ss = 0.f;
    for (int b = 0; b < Bz; ++b) {
        float v = (float)y[((long)b * CH + c) * 256 + t];
        s += v; ss += v * v;
    }
    __shared__ float rs[256], rss[256];
    rs[t] = s; rss[t] = ss; __syncthreads();
    for (int off = 128; off > 0; off >>= 1) {
        if (t < off) { rs[t] += rs[t + off]; rss[t] += rss[t + off]; }
        __syncthreads();
    }
    if (t == 0) {
        float cnt = (float)(Bz * 256);
        float m = rs[0] / cnt;
        float var = rss[0] / cnt - m * m;
        mean[c] = m;
        istd[c] = rsqrtf(var + 1e-5f);
    }
}

// BN1 apply + relu -> scaled hi f16 (d2-lo no longer consumed)
__global__ void bn_apply_relu_kernel(const float* __restrict__ y,
                                     _Float16* __restrict__ yh,
                                     const float* __restrict__ mean, const float* __restrict__ istd,
                                     const float* __restrict__ g, const float* __restrict__ be)
{
    long i = (long)blockIdx.x * 256 + threadIdx.x;
    int c = (int)((i >> 8) % Sz);
    float v = (y[i] - mean[c]) * istd[c] * g[c] + be[c];
    v = fmaxf(v, 0.f);
    yh[i] = (_Float16)(v * SCL);
}

// ---------------------------------------------------------------------------
// Fused BN2-apply + tanh + cosine-similarity output; epre is SCL-scaled f16
__global__ void bn_tanh_out_kernel(const _Float16* __restrict__ epre16,
                                   const float* __restrict__ mean, const float* __restrict__ istd,
                                   const float* __restrict__ g, const float* __restrict__ be,
                                   const float* __restrict__ Vsum, const float* __restrict__ vnorm,
                                   float* __restrict__ out)
{
    int bl = blockIdx.x;               // b*Lz + l
    int l = bl & (Lz - 1);
    int t = threadIdx.x;
    float v = ((float)epre16[(long)bl * 256 + t] - mean[l]) * istd[l] * g[l] + be[l];
    float ev = tanhf(v);
    float vv = Vsum[l * 256 + t];
    __shared__ float rd[256], rn[256];
    rd[t] = ev * vv; rn[t] = ev * ev; __syncthreads();
    for (int off = 128; off > 0; off >>= 1) {
        if (t < off) { rd[t] += rd[t + off]; rn[t] += rn[t + off]; }
        __syncthreads();
    }
    if (t == 0) {
        float num = rd[0];
        float den = fmaxf(sqrtf(rn[0]), 1e-8f) * fmaxf(vnorm[l], 1e-8f);
        out[bl] = num / den * 10.f;
    }
}

// ---------------------------------------------------------------------------
extern "C" void kernel_launch(void* const* d_in, const int* in_sizes, int n_in,
                              void* d_out, int out_size, void* d_ws, size_t ws_size,
                              hipStream_t stream)
{
    const int*   x      = (const int*)d_in[0];
    const int*   V_idx  = (const int*)d_in[1];
    const float* emb    = (const float*)d_in[2];
    const float* w_ih_f = (const float*)d_in[3];
    const float* w_hh_f = (const float*)d_in[4];
    const float* b_ih_f = (const float*)d_in[5];
    const float* b_hh_f = (const float*)d_in[6];
    const float* w_ih_b = (const float*)d_in[7];
    const float* w_hh_b = (const float*)d_in[8];
    const float* b_ih_b = (const float*)d_in[9];
    const float* b_hh_b = (const float*)d_in[10];
    const float* w1     = (const float*)d_in[11];
    const float* b1     = (const float*)d_in[12];
    const float* w2     = (const float*)d_in[13];
    const float* b2     = (const float*)d_in[14];
    const float* g1     = (const float*)d_in[15];
    const float* be1    = (const float*)d_in[16];
    const float* g2     = (const float*)d_in[17];
    const float* be2    = (const float*)d_in[18];

    float* ws = (float*)d_ws;
    float* out = (float*)d_out;

    // ---- workspace layout (float units) ----
    float*    vsum   = ws;                               // 262144
    float*    vnorm  = ws + 262144;                      // 1024
    float*    mean   = ws + 263168;                      // 1024
    float*    istd   = ws + 264192;                      // 1024
    half2_t*  wqf    = (half2_t*)(ws + 265216);          // 98304
    half2_t*  wqb    = (half2_t*)(ws + 363520);          // 98304
    _Float16* vsh    = (_Float16*)(ws + 461824);         // 131072 fl
    _Float16* vsl    = (_Float16*)(ws + 592896);         // 131072 fl
    _Float16* wihh_f = (_Float16*)(ws + 723968);         // 98304 fl
    _Float16* wihl_f = (_Float16*)(ws + 822272);         // 98304 fl
    _Float16* wihh_b = (_Float16*)(ws + 920576);         // 98304 fl (f->b stride 393216 halves)
    _Float16* wihl_b = (_Float16*)(ws + 1018880);        // 98304 fl
    _Float16* w1h    = (_Float16*)(ws + 1117184);        // 65536 fl
    _Float16* w1l    = (_Float16*)(ws + 1182720);        // 65536 fl
    _Float16* w2h    = (_Float16*)(ws + 1248256);        // 65536 fl
    _Float16* w2l    = (_Float16*)(ws + 1313792);        // 65536 fl (produced, unused)
    float*    AB     = ws + 1379328;                     // overlay arena
    _Float16* xeh    = (_Float16*)(AB + 0);              // st1-2 (4.19M fl16)
    _Float16* gx16f  = (_Float16*)(AB + 4194304);        // st2-3: 12.58M halves
    _Float16* gx16b  = (_Float16*)(AB + 10485760);       //        (f->b stride 12582912 halves)
    _Float16* dh     = (_Float16*)(AB + 29360128);       // st3-4 (+dtrans)
    _Float16* dl     = (_Float16*)(AB + 33554432);
    _Float16* dTh    = (_Float16*)(AB + 0);              // dtrans-st6 (xe/gx dead)
    float*    d2pre  = AB + 8388608;                     // st4 (gx dead)
    _Float16* d2h    = (_Float16*)(AB + 12582912);       // st4-5
    _Float16* ah     = (_Float16*)(AB + 16777216);       // st5-6 (gx/d dead)
    _Float16* c16    = (_Float16*)(AB + 33554432);       // st6-7 (dl dead)
    _Float16* epre16 = (_Float16*)(AB + 4194304);        // st7-8 (gx/d2 dead) 33MB

    // Stage 1: gathers + packs
    vsum_kernel<<<Lz, 256, 0, stream>>>(V_idx, emb, vsum, vsh, vsl, vnorm);
    xe_kernel<<<Bz * Sz, 256, 0, stream>>>(x, emb, xeh);
    wpack_kernel<<<384, 256, 0, stream>>>(w_hh_f, w_hh_b, wqf, wqb);
    cvtsplit4_kernel<<<2560, 256, 0, stream>>>(
        w_ih_f, w_ih_b, w1, w2,
        wihh_f, wihl_f, wihh_b, wihl_b, w1h, w1l, w2h, w2l);

    // Stage 2 (merged f+b): gx = xe @ w_ih^T + b_ih (M=16384, N=768, K=256),
    // A hi-only, scaled-f16 out (r14-verified free).
    gemm_mfma<0, 1, 2, 0, 1><<<dim3(6, 128, 2), 256, 0, stream>>>(
        xeh, nullptr, wihh_f, wihl_f, b_ih_f, b_ih_b, nullptr, gx16f, nullptr,
        Bz * Sz, 768, Ez, 0, 393216, 12582912);

    // Stage 3: GRU -> d hi/lo; transpose hi -> dT [B,512,256]
    gru_kernel<<<128, 512, 0, stream>>>(gx16f, gx16b, wqf, wqb, b_hh_f, b_hh_b, dh, dl);
    dtrans_kernel<<<dim3(4, 8, Bz), 256, 0, stream>>>(dh, dTh);

    // Stage 4: d2pre = d @ w1^T + b1 (M=16384, N=256, K=512) f32, FULL splits
    // (a-chain input — r8-proven dangerous class); BN1+relu -> hi f16
    gemm_mfma<0, 1, 0, 1, 1><<<dim3(2, 128, 1), 256, 0, stream>>>(
        dh, dl, w1h, w1l, b1, b1, d2pre, nullptr, nullptr, Bz * Sz, Ez, 512, 0, 0, 0);
    bn_stats_kernel<<<Sz, 256, 0, stream>>>(d2pre, Sz, mean, istd);
    bn_apply_relu_kernel<<<Bz * Sz, 256, 0, stream>>>(d2pre, d2h, mean, istd, g1, be1);

    // Stage 5: a[b] = tanh(Vsum @ d2[b]^T) (M=1024, N=256, K=256) -> hi only.
    // THIS ROUND: d2-lo dropped (SPLIT_B=0; random per-element rounding in a
    // 256-term dot, enters >=1 layer from output) -> 2 passes.
    gemm_mfma<2, 0, 2, 1, 0><<<dim3(2, 8, Bz), 256, 0, stream>>>(
        vsh, vsl, d2h, nullptr, nullptr, nullptr, nullptr, ah, nullptr,
        Lz, Sz, Ez, 0, (long)Sz * Ez, (long)Lz * Sz);

    // Stage 6: c[b] = relu(a[b] @ dT[b]^T) (M=1024, N=512, K=256).
    // THIS ROUND: dT-lo dropped (SPLIT_B=0; c is last-layer-class) -> 1 pass.
    gemm_mfma<1, 0, 2, 0, 0><<<dim3(4, 8, Bz), 256, 0, stream>>>(
        ah, nullptr, dTh, nullptr, nullptr, nullptr, nullptr, c16, nullptr, Lz, 512, Sz,
        (long)Lz * Sz, (long)512 * Sz, (long)Lz * 512);

    // Stage 7: epre = c @ w2^T + b2 (M=65536, N=256, K=512) — single pass,
    // scaled-f16 out (r13-verified free).
    gemm_mfma<0, 1, 2, 0, 0><<<dim3(2, 512, 1), 256, 0, stream>>>(
        c16, nullptr, w2h, nullptr, b2, b2, nullptr, epre16, nullptr,
        Bz * Lz, Ez, 512, 0, 0, 0);
    bn_stats16_kernel<<<Lz, 256, 0, stream>>>(epre16, Lz, mean, istd);

    // Stage 8: fused BN2-apply + tanh + cosine output (f16 epre)
    bn_tanh_out_kernel<<<Bz * Lz, 256, 0, stream>>>(epre16, mean, istd, g2, be2, vsum, vnorm, out);
}